// Round 3
// baseline (14549.046 us; speedup 1.0000x reference)
//
#include <hip/hip_runtime.h>
#include <math.h>

#define B 64
#define TIN 128
#define N_IN 256
#define M 1024
#define O_DIM 512
#define LM 2048
#define TDEC 64
#define M3 3072
#define CH 8     // encoder gi timestep chunk
#define NB 128   // grid blocks for the two mega-kernels (co-residency safe)

typedef short bf16x8 __attribute__((ext_vector_type(8)));
typedef float floatx4 __attribute__((ext_vector_type(4)));

__device__ __forceinline__ unsigned short f2bf(float f) {
    unsigned int u = __float_as_uint(f);
    u += 0x7FFFu + ((u >> 16) & 1u);      // round-to-nearest-even
    return (unsigned short)(u >> 16);
}
__device__ __forceinline__ float sigm(float x) { return 1.f / (1.f + expf(-x)); }

// ---------------------------------------------------------------------------
// Grid barrier: epoch-counting, agent-scope atomics (cross-XCD correct).
// Release on arrival publishes this block's writes; acquire on exit.
// Bounded spin as a hang escape-hatch (should never trigger).
// ---------------------------------------------------------------------------
__device__ __forceinline__ void gridbar(unsigned* cnt, unsigned* eps, unsigned epoch) {
    __syncthreads();
    if (threadIdx.x == 0) {
        unsigned old = __hip_atomic_fetch_add(cnt, 1u, __ATOMIC_ACQ_REL,
                                              __HIP_MEMORY_SCOPE_AGENT);
        if (old == NB - 1) {
            __hip_atomic_store(cnt, 0u, __ATOMIC_RELAXED, __HIP_MEMORY_SCOPE_AGENT);
            __hip_atomic_store(eps, epoch, __ATOMIC_RELEASE, __HIP_MEMORY_SCOPE_AGENT);
        } else {
            unsigned guard = 0;
            while (__hip_atomic_load(eps, __ATOMIC_RELAXED,
                                     __HIP_MEMORY_SCOPE_AGENT) < epoch) {
                __builtin_amdgcn_s_sleep(2);
                if (++guard > (1u << 24)) break;   // escape: fail loud, don't hang
            }
            __builtin_amdgcn_fence(__ATOMIC_ACQUIRE, "agent");
        }
    }
    __syncthreads();
}

// ---------------------------------------------------------------------------
// fp32 -> bf16 cast (weights, Y0)
// ---------------------------------------------------------------------------
__global__ __launch_bounds__(256) void cast_bf(const float* __restrict__ in,
                                               short* __restrict__ out, int n) {
    int i = blockIdx.x * 256 + threadIdx.x;
    if (i < n) out[i] = (short)f2bf(in[i]);
}

// ---------------------------------------------------------------------------
// X (B,TIN,N) fp32 -> Xt (TIN,B,N) bf16
// ---------------------------------------------------------------------------
__global__ __launch_bounds__(256) void transpose_X_bf(const float* __restrict__ X,
                                                      short* __restrict__ Xt) {
    int idx = blockIdx.x * 256 + threadIdx.x;   // t*(B*N) + b*N + n
    int n = idx & (N_IN - 1);
    int b = (idx >> 8) & (B - 1);
    int t = idx >> 14;
    Xt[idx] = (short)f2bf(X[(b * TIN + t) * N_IN + n]);
}

// ===========================================================================
// ENCODER mega-kernel: per layer, per chunk: GI GEMM phase -> 8 GRU steps.
// grid = NB x 256. Barriers separate phases.
// ===========================================================================
struct EncArgs {
    const short* Xt;       // (TIN,B,N) bf16
    short* seqA;           // (TIN,B,M) bf16   layer-0 outputs
    float* gi;             // (CH,B,M3) fp32   chunk scratch
    const short* wih0; const short* whh0; const float* bih0; const float* bhh0;
    const short* wih1; const short* whh1; const float* bih1; const float* bhh1;
    float* h0f; float* h1f;
    short* h0b; short* h1b;      // ping-pong (2,B,M)
    unsigned* cnt; unsigned* eps;
};

__global__ __launch_bounds__(256, 1) void enc_mega(EncArgs a) {
    __shared__ float lds[2][3][4][64][4];       // 24 KB
    const int bid  = blockIdx.x;
    const int wave = threadIdx.x >> 6;
    const int lane = threadIdx.x & 63;
    const int lrow = lane & 15;
    const int ko8  = (lane >> 4) * 8;
    unsigned epoch = 0;

    for (int layer = 0; layer < 2; ++layer) {
        const short* Wih = layer ? a.wih1 : a.wih0;
        const short* Whh = layer ? a.whh1 : a.whh0;
        const float* bih = layer ? a.bih1 : a.bih0;
        const float* bhh = layer ? a.bhh1 : a.bhh0;
        const short* inseq = layer ? a.seqA : a.Xt;
        const int K = layer ? M : N_IN;
        float* hf = layer ? a.h1f : a.h0f;
        short* hb = layer ? a.h1b : a.h0b;

        for (int c = 0; c < TIN / CH; ++c) {
            // ---- GI phase: gi[tt,b,:] = inseq[chunk] @ Wih^T + bih ----
            // 512 rows x 192 col-tiles = 6144 tiles over 512 waves -> 12/wave
            {
                const short* A = inseq + (size_t)c * CH * B * K;
                int gw = bid * 4 + wave;               // 0..511
                for (int i = 0; i < 12; ++i) {
                    int tile = gw * 12 + i;            // 0..6143
                    int r0 = (tile / 192) * 16;
                    int c0 = (tile % 192) * 16;
                    const short* ap = A + (size_t)(r0 + lrow) * K + ko8;
                    const short* wp = Wih + (size_t)(c0 + lrow) * K + ko8;
                    floatx4 acc = {0.f, 0.f, 0.f, 0.f};
                    #pragma unroll 4
                    for (int k = 0; k < K; k += 32) {
                        bf16x8 av = *(const bf16x8*)(ap + k);
                        bf16x8 bv = *(const bf16x8*)(wp + k);
                        acc = __builtin_amdgcn_mfma_f32_16x16x32_bf16(av, bv, acc, 0, 0, 0);
                    }
                    int col = c0 + lrow;
                    float bv = bih[col];
                    int rb = r0 + (lane >> 4) * 4;
                    #pragma unroll
                    for (int q = 0; q < 4; q++)
                        a.gi[(size_t)(rb + q) * M3 + col] = acc[q] + bv;
                }
            }
            gridbar(a.cnt, a.eps, ++epoch);
            // ---- 8 GRU steps; each block owns 2 m-tiles (shared batch rows)
            for (int tt = 0; tt < CH; ++tt) {
                int t = c * CH + tt;
                int pin = t & 1, pout = pin ^ 1;
                const short* h_in = hb + (size_t)pin * B * M;
                const float* gi_t = a.gi + (size_t)tt * B * M3;
                int r0 = (bid & 3) * 16;
                const int Kq = M >> 2;                 // 256
                const short* ap0 = h_in + (size_t)(r0 + lrow) * M + wave * Kq + ko8;
                const short *wr[2], *wz[2], *wn[2];
                #pragma unroll
                for (int j = 0; j < 2; ++j) {
                    int m0 = (j * 32 + (bid >> 2)) * 16;
                    wr[j] = Whh + (size_t)(m0 + lrow) * M + wave * Kq + ko8;
                    wz[j] = wr[j] + (size_t)M * M;
                    wn[j] = wr[j] + (size_t)2 * M * M;
                }
                floatx4 ar[2], az[2], ah[2];
                #pragma unroll
                for (int j = 0; j < 2; ++j) {
                    ar[j] = (floatx4){0.f, 0.f, 0.f, 0.f};
                    az[j] = (floatx4){0.f, 0.f, 0.f, 0.f};
                    ah[j] = (floatx4){0.f, 0.f, 0.f, 0.f};
                }
                #pragma unroll
                for (int k = 0; k < Kq; k += 32) {
                    bf16x8 av = *(const bf16x8*)(ap0 + k);
                    #pragma unroll
                    for (int j = 0; j < 2; ++j) {
                        ar[j] = __builtin_amdgcn_mfma_f32_16x16x32_bf16(av, *(const bf16x8*)(wr[j] + k), ar[j], 0, 0, 0);
                        az[j] = __builtin_amdgcn_mfma_f32_16x16x32_bf16(av, *(const bf16x8*)(wz[j] + k), az[j], 0, 0, 0);
                        ah[j] = __builtin_amdgcn_mfma_f32_16x16x32_bf16(av, *(const bf16x8*)(wn[j] + k), ah[j], 0, 0, 0);
                    }
                }
                #pragma unroll
                for (int j = 0; j < 2; ++j)
                    #pragma unroll
                    for (int i = 0; i < 4; i++) {
                        lds[j][0][wave][lane][i] = ar[j][i];
                        lds[j][1][wave][lane][i] = az[j][i];
                        lds[j][2][wave][lane][i] = ah[j][i];
                    }
                __syncthreads();
                int row = threadIdx.x >> 4, col = threadIdx.x & 15;
                int sl = (row >> 2) * 16 + col, rg = row & 3;
                int b = r0 + row;
                const float* gir = gi_t + (size_t)b * M3;
                #pragma unroll
                for (int j = 0; j < 2; ++j) {
                    int m0 = (j * 32 + (bid >> 2)) * 16;
                    int m = m0 + col;
                    float sr = lds[j][0][0][sl][rg] + lds[j][0][1][sl][rg] + lds[j][0][2][sl][rg] + lds[j][0][3][sl][rg];
                    float sz = lds[j][1][0][sl][rg] + lds[j][1][1][sl][rg] + lds[j][1][2][sl][rg] + lds[j][1][3][sl][rg];
                    float sn = lds[j][2][0][sl][rg] + lds[j][2][1][sl][rg] + lds[j][2][2][sl][rg] + lds[j][2][3][sl][rg];
                    float r = sigm(gir[m] + sr + bhh[m]);
                    float z = sigm(gir[M + m] + sz + bhh[M + m]);
                    float n = tanhf(gir[2 * M + m] + r * (sn + bhh[2 * M + m]));
                    size_t hi = (size_t)b * M + m;
                    float hv = (1.f - z) * n + z * hf[hi];
                    hf[hi] = hv;
                    short hbv = (short)f2bf(hv);
                    hb[(size_t)pout * B * M + hi] = hbv;
                    if (layer == 0) a.seqA[(size_t)t * B * M + hi] = hbv;
                }
                gridbar(a.cnt, a.eps, ++epoch);
            }
        }
    }
}

// ===========================================================================
// DECODER mega-kernel: 5 barrier-separated phases per step.
// grid = NB x 256.
// ===========================================================================
struct DecArgs {
    const short* yb;                         // (B,O) bf16 initial y
    const short* wih0; const short* whh0; const float* bih0; const float* bhh0;
    const short* wih1; const short* whh1; const float* bih1; const float* bhh1;
    const short* wfc1; const float* fc1b;
    const float* lng; const float* lnb;
    const short* wfc2; const float* fc2b;
    float* h0f; float* h1f;
    short* h0b; short* h1b;                  // ping-pong (2,B,M)
    float* zb;                               // (B,LM) fp32
    short* zbb;                              // (B,LM) bf16
    float* stats;                            // (TDEC,2,B) fp32, pre-zeroed
    float* out;                              // (B,TDEC,O) fp32 logits (output)
    unsigned* cnt; unsigned* eps;
};

__global__ __launch_bounds__(256, 1) void dec_mega(DecArgs a) {
    __shared__ short xs[16 * O_DIM];         // 16 KB, XOR-swizzled A rows
    __shared__ float lds[2][4][4][64][4];    // 32 KB
    const int bid  = blockIdx.x;
    const int wave = threadIdx.x >> 6;
    const int lane = threadIdx.x & 63;
    const int lrow = lane & 15;
    const int ko8  = (lane >> 4) * 8;
    const int ldl  = TDEC * O_DIM;
    unsigned epoch = 0;

    for (int t = 0; t < TDEC; ++t) {
        int pin = t & 1, pout = pin ^ 1;
        int r0 = (bid & 3) * 16;
        // ============ Phase A: gru0 + fused softmax(prev logits) ===========
        {
            int rr = wave * 4 + (lane >> 4);       // row 0..15 of this block
            int cl = lane & 15;
            if (t > 0) {
                const float* rowp = a.out + (size_t)(r0 + rr) * ldl
                                  + (size_t)(t - 1) * O_DIM + cl * 32;
                float v[32];
                float mx = -3.4e38f;
                #pragma unroll
                for (int j = 0; j < 32; j++) { v[j] = rowp[j]; mx = fmaxf(mx, v[j]); }
                #pragma unroll
                for (int off = 1; off < 16; off <<= 1) mx = fmaxf(mx, __shfl_xor(mx, off, 16));
                float s = 0.f;
                #pragma unroll
                for (int j = 0; j < 32; j++) { v[j] = __expf(v[j] - mx); s += v[j]; }
                #pragma unroll
                for (int off = 1; off < 16; off <<= 1) s += __shfl_xor(s, off, 16);
                float inv = 1.f / s;
                #pragma unroll
                for (int j = 0; j < 32; j += 2) {
                    unsigned int pk = (unsigned int)f2bf(v[j] * inv)
                                    | ((unsigned int)f2bf(v[j + 1] * inv) << 16);
                    int byte = ((rr * O_DIM + cl * 32 + j) * 2) ^ ((rr & 7) << 4);
                    *(unsigned int*)((char*)xs + byte) = pk;
                }
            } else {
                const short* rowp = a.yb + (size_t)(r0 + rr) * O_DIM + cl * 32;
                #pragma unroll
                for (int j = 0; j < 32; j += 2) {
                    unsigned int pk = (unsigned int)(unsigned short)rowp[j]
                                    | ((unsigned int)(unsigned short)rowp[j + 1] << 16);
                    int byte = ((rr * O_DIM + cl * 32 + j) * 2) ^ ((rr & 7) << 4);
                    *(unsigned int*)((char*)xs + byte) = pk;
                }
            }
            __syncthreads();
            const int KqI = O_DIM >> 2;            // 128
            const int KqH = M >> 2;                // 256
            const short *wrI[2], *wzI[2], *wnI[2], *wrH[2], *wzH[2], *wnH[2];
            #pragma unroll
            for (int j = 0; j < 2; ++j) {
                int m0 = (j * 32 + (bid >> 2)) * 16;
                wrI[j] = a.wih0 + (size_t)(m0 + lrow) * O_DIM + wave * KqI + ko8;
                wzI[j] = wrI[j] + (size_t)M * O_DIM;
                wnI[j] = wrI[j] + (size_t)2 * M * O_DIM;
                wrH[j] = a.whh0 + (size_t)(m0 + lrow) * M + wave * KqH + ko8;
                wzH[j] = wrH[j] + (size_t)M * M;
                wnH[j] = wrH[j] + (size_t)2 * M * M;
            }
            floatx4 ar[2], az[2], ai[2], ah[2];
            #pragma unroll
            for (int j = 0; j < 2; ++j) {
                ar[j] = (floatx4){0.f, 0.f, 0.f, 0.f};
                az[j] = (floatx4){0.f, 0.f, 0.f, 0.f};
                ai[j] = (floatx4){0.f, 0.f, 0.f, 0.f};
                ah[j] = (floatx4){0.f, 0.f, 0.f, 0.f};
            }
            #pragma unroll
            for (int k = 0; k < KqI; k += 32) {
                int abyte = ((lrow * O_DIM + wave * KqI + ko8 + k) * 2) ^ ((lrow & 7) << 4);
                bf16x8 av = *(const bf16x8*)((const char*)xs + abyte);
                #pragma unroll
                for (int j = 0; j < 2; ++j) {
                    ar[j] = __builtin_amdgcn_mfma_f32_16x16x32_bf16(av, *(const bf16x8*)(wrI[j] + k), ar[j], 0, 0, 0);
                    az[j] = __builtin_amdgcn_mfma_f32_16x16x32_bf16(av, *(const bf16x8*)(wzI[j] + k), az[j], 0, 0, 0);
                    ai[j] = __builtin_amdgcn_mfma_f32_16x16x32_bf16(av, *(const bf16x8*)(wnI[j] + k), ai[j], 0, 0, 0);
                }
            }
            const short* apH = a.h0b + (size_t)pin * B * M + (size_t)(r0 + lrow) * M + wave * KqH + ko8;
            #pragma unroll
            for (int k = 0; k < KqH; k += 32) {
                bf16x8 av = *(const bf16x8*)(apH + k);
                #pragma unroll
                for (int j = 0; j < 2; ++j) {
                    ar[j] = __builtin_amdgcn_mfma_f32_16x16x32_bf16(av, *(const bf16x8*)(wrH[j] + k), ar[j], 0, 0, 0);
                    az[j] = __builtin_amdgcn_mfma_f32_16x16x32_bf16(av, *(const bf16x8*)(wzH[j] + k), az[j], 0, 0, 0);
                    ah[j] = __builtin_amdgcn_mfma_f32_16x16x32_bf16(av, *(const bf16x8*)(wnH[j] + k), ah[j], 0, 0, 0);
                }
            }
            #pragma unroll
            for (int j = 0; j < 2; ++j)
                #pragma unroll
                for (int i = 0; i < 4; i++) {
                    lds[j][0][wave][lane][i] = ar[j][i];
                    lds[j][1][wave][lane][i] = az[j][i];
                    lds[j][2][wave][lane][i] = ai[j][i];
                    lds[j][3][wave][lane][i] = ah[j][i];
                }
            __syncthreads();
            int row = threadIdx.x >> 4, col = threadIdx.x & 15;
            int sl = (row >> 2) * 16 + col, rg = row & 3;
            int b = r0 + row;
            #pragma unroll
            for (int j = 0; j < 2; ++j) {
                int m0 = (j * 32 + (bid >> 2)) * 16;
                int m = m0 + col;
                float sr = lds[j][0][0][sl][rg] + lds[j][0][1][sl][rg] + lds[j][0][2][sl][rg] + lds[j][0][3][sl][rg];
                float sz = lds[j][1][0][sl][rg] + lds[j][1][1][sl][rg] + lds[j][1][2][sl][rg] + lds[j][1][3][sl][rg];
                float si = lds[j][2][0][sl][rg] + lds[j][2][1][sl][rg] + lds[j][2][2][sl][rg] + lds[j][2][3][sl][rg];
                float sh = lds[j][3][0][sl][rg] + lds[j][3][1][sl][rg] + lds[j][3][2][sl][rg] + lds[j][3][3][sl][rg];
                float r = sigm(sr + a.bih0[m] + a.bhh0[m]);
                float z = sigm(sz + a.bih0[M + m] + a.bhh0[M + m]);
                float n = tanhf(si + a.bih0[2 * M + m] + r * (sh + a.bhh0[2 * M + m]));
                size_t hi = (size_t)b * M + m;
                float hv = (1.f - z) * n + z * a.h0f[hi];
                a.h0f[hi] = hv;
                a.h0b[(size_t)pout * B * M + hi] = (short)f2bf(hv);
            }
        }
        gridbar(a.cnt, a.eps, ++epoch);
        // ============ Phase B: gru1 (x = new h0, Kx = M) ===================
        {
            const int Kq = M >> 2;
            const short *wrI[2], *wzI[2], *wnI[2], *wrH[2], *wzH[2], *wnH[2];
            #pragma unroll
            for (int j = 0; j < 2; ++j) {
                int m0 = (j * 32 + (bid >> 2)) * 16;
                wrI[j] = a.wih1 + (size_t)(m0 + lrow) * M + wave * Kq + ko8;
                wzI[j] = wrI[j] + (size_t)M * M;
                wnI[j] = wrI[j] + (size_t)2 * M * M;
                wrH[j] = a.whh1 + (size_t)(m0 + lrow) * M + wave * Kq + ko8;
                wzH[j] = wrH[j] + (size_t)M * M;
                wnH[j] = wrH[j] + (size_t)2 * M * M;
            }
            floatx4 ar[2], az[2], ai[2], ah[2];
            #pragma unroll
            for (int j = 0; j < 2; ++j) {
                ar[j] = (floatx4){0.f, 0.f, 0.f, 0.f};
                az[j] = (floatx4){0.f, 0.f, 0.f, 0.f};
                ai[j] = (floatx4){0.f, 0.f, 0.f, 0.f};
                ah[j] = (floatx4){0.f, 0.f, 0.f, 0.f};
            }
            const short* apI = a.h0b + (size_t)pout * B * M + (size_t)(r0 + lrow) * M + wave * Kq + ko8;
            #pragma unroll
            for (int k = 0; k < Kq; k += 32) {
                bf16x8 av = *(const bf16x8*)(apI + k);
                #pragma unroll
                for (int j = 0; j < 2; ++j) {
                    ar[j] = __builtin_amdgcn_mfma_f32_16x16x32_bf16(av, *(const bf16x8*)(wrI[j] + k), ar[j], 0, 0, 0);
                    az[j] = __builtin_amdgcn_mfma_f32_16x16x32_bf16(av, *(const bf16x8*)(wzI[j] + k), az[j], 0, 0, 0);
                    ai[j] = __builtin_amdgcn_mfma_f32_16x16x32_bf16(av, *(const bf16x8*)(wnI[j] + k), ai[j], 0, 0, 0);
                }
            }
            const short* apH = a.h1b + (size_t)pin * B * M + (size_t)(r0 + lrow) * M + wave * Kq + ko8;
            #pragma unroll
            for (int k = 0; k < Kq; k += 32) {
                bf16x8 av = *(const bf16x8*)(apH + k);
                #pragma unroll
                for (int j = 0; j < 2; ++j) {
                    ar[j] = __builtin_amdgcn_mfma_f32_16x16x32_bf16(av, *(const bf16x8*)(wrH[j] + k), ar[j], 0, 0, 0);
                    az[j] = __builtin_amdgcn_mfma_f32_16x16x32_bf16(av, *(const bf16x8*)(wzH[j] + k), az[j], 0, 0, 0);
                    ah[j] = __builtin_amdgcn_mfma_f32_16x16x32_bf16(av, *(const bf16x8*)(wnH[j] + k), ah[j], 0, 0, 0);
                }
            }
            #pragma unroll
            for (int j = 0; j < 2; ++j)
                #pragma unroll
                for (int i = 0; i < 4; i++) {
                    lds[j][0][wave][lane][i] = ar[j][i];
                    lds[j][1][wave][lane][i] = az[j][i];
                    lds[j][2][wave][lane][i] = ai[j][i];
                    lds[j][3][wave][lane][i] = ah[j][i];
                }
            __syncthreads();
            int row = threadIdx.x >> 4, col = threadIdx.x & 15;
            int sl = (row >> 2) * 16 + col, rg = row & 3;
            int b = r0 + row;
            #pragma unroll
            for (int j = 0; j < 2; ++j) {
                int m0 = (j * 32 + (bid >> 2)) * 16;
                int m = m0 + col;
                float sr = lds[j][0][0][sl][rg] + lds[j][0][1][sl][rg] + lds[j][0][2][sl][rg] + lds[j][0][3][sl][rg];
                float sz = lds[j][1][0][sl][rg] + lds[j][1][1][sl][rg] + lds[j][1][2][sl][rg] + lds[j][1][3][sl][rg];
                float si = lds[j][2][0][sl][rg] + lds[j][2][1][sl][rg] + lds[j][2][2][sl][rg] + lds[j][2][3][sl][rg];
                float sh = lds[j][3][0][sl][rg] + lds[j][3][1][sl][rg] + lds[j][3][2][sl][rg] + lds[j][3][3][sl][rg];
                float r = sigm(sr + a.bih1[m] + a.bhh1[m]);
                float z = sigm(sz + a.bih1[M + m] + a.bhh1[M + m]);
                float n = tanhf(si + a.bih1[2 * M + m] + r * (sh + a.bhh1[2 * M + m]));
                size_t hi = (size_t)b * M + m;
                float hv = (1.f - z) * n + z * a.h1f[hi];
                a.h1f[hi] = hv;
                a.h1b[(size_t)pout * B * M + hi] = (short)f2bf(hv);
            }
        }
        gridbar(a.cnt, a.eps, ++epoch);
        // ============ Phase C: fc1 (4 col-tiles/block) + LN stats ==========
        {
            float* st = a.stats + (size_t)t * 2 * B;
            const int Kq = M >> 2;
            const short* ap = a.h1b + (size_t)pout * B * M + (size_t)(r0 + lrow) * M + wave * Kq + ko8;
            const short* wp[4];
            floatx4 acc[4];
            #pragma unroll
            for (int j = 0; j < 4; ++j) {
                int c0 = (j * 32 + (bid >> 2)) * 16;
                wp[j] = a.wfc1 + (size_t)(c0 + lrow) * M + wave * Kq + ko8;
                acc[j] = (floatx4){0.f, 0.f, 0.f, 0.f};
            }
            #pragma unroll
            for (int k = 0; k < Kq; k += 32) {
                bf16x8 av = *(const bf16x8*)(ap + k);
                #pragma unroll
                for (int j = 0; j < 4; ++j)
                    acc[j] = __builtin_amdgcn_mfma_f32_16x16x32_bf16(av, *(const bf16x8*)(wp[j] + k), acc[j], 0, 0, 0);
            }
            #pragma unroll
            for (int j = 0; j < 4; ++j)
                #pragma unroll
                for (int i = 0; i < 4; i++) lds[0][j][wave][lane][i] = acc[j][i];
            __syncthreads();
            int row = threadIdx.x >> 4, col = threadIdx.x & 15;
            int sl = (row >> 2) * 16 + col, rg = row & 3;
            #pragma unroll
            for (int j = 0; j < 4; ++j) {
                int c0 = (j * 32 + (bid >> 2)) * 16;
                float s = lds[0][j][0][sl][rg] + lds[0][j][1][sl][rg]
                        + lds[0][j][2][sl][rg] + lds[0][j][3][sl][rg];
                float val = s + a.fc1b[c0 + col];
                a.zb[(size_t)(r0 + row) * LM + c0 + col] = val;
                float sv = val, sq = val * val;
                #pragma unroll
                for (int off = 1; off < 16; off <<= 1) {
                    sv += __shfl_xor(sv, off, 16);
                    sq += __shfl_xor(sq, off, 16);
                }
                if ((threadIdx.x & 15) == 0) {
                    atomicAdd(&st[r0 + row], sv);
                    atomicAdd(&st[B + r0 + row], sq);
                }
            }
        }
        gridbar(a.cnt, a.eps, ++epoch);
        // ============ Phase D: LN + GELU apply (4 elems/thread) ============
        {
            const float* st = a.stats + (size_t)t * 2 * B;
            int e0 = (bid * 256 + threadIdx.x) * 4;      // B*LM = 131072
            int rowd = e0 >> 11;
            float mu = st[rowd] * (1.f / LM);
            float var = st[B + rowd] * (1.f / LM) - mu * mu;
            float inv = rsqrtf(var + 1e-5f);
            #pragma unroll
            for (int j = 0; j < 4; j++) {
                int e = e0 + j;
                int cc = e & (LM - 1);
                float zn = (a.zb[e] - mu) * inv * a.lng[cc] + a.lnb[cc];
                float ge = 0.5f * zn * (1.f + erff(zn * 0.70710678118654752f));
                a.zbb[e] = (short)f2bf(ge);
            }
        }
        gridbar(a.cnt, a.eps, ++epoch);
        // ============ Phase E: fc2 -> logits out[:, t, :] ==================
        {
            int c0 = (bid >> 2) * 16;
            const int Kq = LM >> 2;                      // 512
            const short* ap = a.zbb + (size_t)(r0 + lrow) * LM + wave * Kq + ko8;
            const short* wpp = a.wfc2 + (size_t)(c0 + lrow) * LM + wave * Kq + ko8;
            floatx4 acc = {0.f, 0.f, 0.f, 0.f};
            #pragma unroll 4
            for (int k = 0; k < Kq; k += 32) {
                bf16x8 av = *(const bf16x8*)(ap + k);
                bf16x8 bv = *(const bf16x8*)(wpp + k);
                acc = __builtin_amdgcn_mfma_f32_16x16x32_bf16(av, bv, acc, 0, 0, 0);
            }
            #pragma unroll
            for (int i = 0; i < 4; i++) lds[0][0][wave][lane][i] = acc[i];
            __syncthreads();
            int row = threadIdx.x >> 4, col = threadIdx.x & 15;
            int sl = (row >> 2) * 16 + col, rg = row & 3;
            float s = lds[0][0][0][sl][rg] + lds[0][0][1][sl][rg]
                    + lds[0][0][2][sl][rg] + lds[0][0][3][sl][rg];
            a.out[(size_t)(r0 + row) * ldl + (size_t)t * O_DIM + c0 + col]
                = s + a.fc2b[c0 + col];
        }
        gridbar(a.cnt, a.eps, ++epoch);
    }
}

// ===========================================================================
extern "C" void kernel_launch(void* const* d_in, const int* in_sizes, int n_in,
                              void* d_out, int out_size, void* d_ws, size_t ws_size,
                              hipStream_t stream) {
    const float* X        = (const float*)d_in[0];
    const float* Y0       = (const float*)d_in[1];
    const float* enc_Wih0 = (const float*)d_in[2];
    const float* enc_Whh0 = (const float*)d_in[3];
    const float* enc_bih0 = (const float*)d_in[4];
    const float* enc_bhh0 = (const float*)d_in[5];
    const float* enc_Wih1 = (const float*)d_in[6];
    const float* enc_Whh1 = (const float*)d_in[7];
    const float* enc_bih1 = (const float*)d_in[8];
    const float* enc_bhh1 = (const float*)d_in[9];
    const float* dec_Wih0 = (const float*)d_in[10];
    const float* dec_Whh0 = (const float*)d_in[11];
    const float* dec_bih0 = (const float*)d_in[12];
    const float* dec_bhh0 = (const float*)d_in[13];
    const float* dec_Wih1 = (const float*)d_in[14];
    const float* dec_Whh1 = (const float*)d_in[15];
    const float* dec_bih1 = (const float*)d_in[16];
    const float* dec_bhh1 = (const float*)d_in[17];
    const float* fc1_w    = (const float*)d_in[18];
    const float* fc1_b    = (const float*)d_in[19];
    const float* ln_g     = (const float*)d_in[20];
    const float* ln_b     = (const float*)d_in[21];
    const float* fc2_w    = (const float*)d_in[22];
    const float* fc2_b    = (const float*)d_in[23];
    float* out = (float*)d_out;

    // ---- workspace carve-up ----
    char* p = (char*)d_ws;
    auto carve = [&](size_t bytes) {
        void* r = p;
        p += (bytes + 255) & ~(size_t)255;
        return r;
    };
    short* Xt    = (short*)carve((size_t)TIN * B * N_IN * 2);
    short* seqA  = (short*)carve((size_t)TIN * B * M * 2);
    float* gi_ch = (float*)carve((size_t)CH * B * M3 * 4);
    short* we_ih0 = (short*)carve((size_t)M3 * N_IN * 2);
    short* we_hh0 = (short*)carve((size_t)M3 * M * 2);
    short* we_ih1 = (short*)carve((size_t)M3 * M * 2);
    short* we_hh1 = (short*)carve((size_t)M3 * M * 2);
    short* wd_ih0 = (short*)carve((size_t)M3 * O_DIM * 2);
    short* wd_hh0 = (short*)carve((size_t)M3 * M * 2);
    short* wd_ih1 = (short*)carve((size_t)M3 * M * 2);
    short* wd_hh1 = (short*)carve((size_t)M3 * M * 2);
    short* wfc1   = (short*)carve((size_t)LM * M * 2);
    short* wfc2   = (short*)carve((size_t)O_DIM * LM * 2);
    float* h0f = (float*)carve((size_t)B * M * 4);
    float* h1f = (float*)carve((size_t)B * M * 4);
    short* h0b = (short*)carve((size_t)2 * B * M * 2);   // ping-pong
    short* h1b = (short*)carve((size_t)2 * B * M * 2);
    short* yb  = (short*)carve((size_t)B * O_DIM * 2);
    float* zb  = (float*)carve((size_t)B * LM * 4);
    short* zbb = (short*)carve((size_t)B * LM * 2);
    float* lnstats = (float*)carve((size_t)TDEC * 2 * B * 4);
    unsigned* ebar = (unsigned*)carve(256);              // [cnt, eps]
    unsigned* dbar = (unsigned*)carve(256);

    auto cast = [&](const float* src, short* dst, int n) {
        cast_bf<<<(n + 255) / 256, 256, 0, stream>>>(src, dst, n);
    };
    cast(enc_Wih0, we_ih0, M3 * N_IN);
    cast(enc_Whh0, we_hh0, M3 * M);
    cast(enc_Wih1, we_ih1, M3 * M);
    cast(enc_Whh1, we_hh1, M3 * M);
    cast(dec_Wih0, wd_ih0, M3 * O_DIM);
    cast(dec_Whh0, wd_hh0, M3 * M);
    cast(dec_Wih1, wd_ih1, M3 * M);
    cast(dec_Whh1, wd_hh1, M3 * M);
    cast(fc1_w, wfc1, LM * M);
    cast(fc2_w, wfc2, O_DIM * LM);
    cast(Y0, yb, B * O_DIM);
    transpose_X_bf<<<(TIN * B * N_IN) / 256, 256, 0, stream>>>(X, Xt);

    hipMemsetAsync(h0f, 0, (size_t)B * M * 4, stream);
    hipMemsetAsync(h1f, 0, (size_t)B * M * 4, stream);
    hipMemsetAsync(h0b, 0, (size_t)B * M * 2, stream);   // parity-0 buffer
    hipMemsetAsync(h1b, 0, (size_t)B * M * 2, stream);
    hipMemsetAsync(lnstats, 0, (size_t)TDEC * 2 * B * 4, stream);
    hipMemsetAsync(ebar, 0, 256, stream);
    hipMemsetAsync(dbar, 0, 256, stream);

    // -------------------- encoder (one mega-kernel) -----------------------
    EncArgs ea;
    ea.Xt = Xt; ea.seqA = seqA; ea.gi = gi_ch;
    ea.wih0 = we_ih0; ea.whh0 = we_hh0; ea.bih0 = enc_bih0; ea.bhh0 = enc_bhh0;
    ea.wih1 = we_ih1; ea.whh1 = we_hh1; ea.bih1 = enc_bih1; ea.bhh1 = enc_bhh1;
    ea.h0f = h0f; ea.h1f = h1f; ea.h0b = h0b; ea.h1b = h1b;
    ea.cnt = ebar; ea.eps = ebar + 16;
    enc_mega<<<dim3(NB), dim3(256), 0, stream>>>(ea);

    // -------------------- decoder (one mega-kernel) -----------------------
    DecArgs da;
    da.yb = yb;
    da.wih0 = wd_ih0; da.whh0 = wd_hh0; da.bih0 = dec_bih0; da.bhh0 = dec_bhh0;
    da.wih1 = wd_ih1; da.whh1 = wd_hh1; da.bih1 = dec_bih1; da.bhh1 = dec_bhh1;
    da.wfc1 = wfc1; da.fc1b = fc1_b;
    da.lng = ln_g; da.lnb = ln_b;
    da.wfc2 = wfc2; da.fc2b = fc2_b;
    da.h0f = h0f; da.h1f = h1f; da.h0b = h0b; da.h1b = h1b;
    da.zb = zb; da.zbb = zbb; da.stats = lnstats; da.out = out;
    da.cnt = dbar; da.eps = dbar + 16;
    dec_mega<<<dim3(NB), dim3(256), 0, stream>>>(da);
}

// Round 5
// 11066.485 us; speedup vs baseline: 1.3147x; 1.3147x over previous
//
#include <hip/hip_runtime.h>
#include <math.h>

#define B 64
#define TIN 128
#define N_IN 256
#define M 1024
#define O_DIM 512
#define LM 2048
#define TDEC 64
#define M3 3072
#define CH 8     // encoder gi timestep chunk
#define NB 256   // grid blocks for the two mega-kernels (1 block/CU)

typedef short bf16x8 __attribute__((ext_vector_type(8)));
typedef float floatx4 __attribute__((ext_vector_type(4)));

__device__ __forceinline__ unsigned short f2bf(float f) {
    unsigned int u = __float_as_uint(f);
    u += 0x7FFFu + ((u >> 16) & 1u);      // round-to-nearest-even
    return (unsigned short)(u >> 16);
}
__device__ __forceinline__ float sigm(float x) { return 1.f / (1.f + expf(-x)); }

// ---------------------------------------------------------------------------
// Grid barrier, decentralized: per-block padded arrival flags (parallel
// release-stores, no cacheline ping-pong), block-0 polls all flags with one
// lane each (parallel), then broadcasts the epoch. Release/acquire chain:
// arrival(release) -> master(acquire all) -> broadcast(release) ->
// waiter(acquire). Bounded spins as hang escape hatches.
// ---------------------------------------------------------------------------
__device__ __forceinline__ void gridbar(unsigned* flags, unsigned* eps,
                                        unsigned epoch, int bid) {
    __syncthreads();
    if (threadIdx.x == 0)
        __hip_atomic_store(&flags[(size_t)bid * 32], epoch, __ATOMIC_RELEASE,
                           __HIP_MEMORY_SCOPE_AGENT);
    if (bid == 0) {
        // 256 threads each own one flag
        unsigned guard = 0;
        while (__hip_atomic_load(&flags[(size_t)threadIdx.x * 32],
                                 __ATOMIC_RELAXED,
                                 __HIP_MEMORY_SCOPE_AGENT) < epoch) {
            __builtin_amdgcn_s_sleep(2);
            if (++guard > (1u << 22)) break;   // escape: fail loud, don't hang
        }
        __builtin_amdgcn_fence(__ATOMIC_ACQUIRE, "agent");
        __syncthreads();
        if (threadIdx.x == 0)
            __hip_atomic_store(eps, epoch, __ATOMIC_RELEASE,
                               __HIP_MEMORY_SCOPE_AGENT);
    } else if (threadIdx.x == 0) {
        unsigned guard = 0;
        while (__hip_atomic_load(eps, __ATOMIC_RELAXED,
                                 __HIP_MEMORY_SCOPE_AGENT) < epoch) {
            __builtin_amdgcn_s_sleep(2);
            if (++guard > (1u << 22)) break;
        }
        __builtin_amdgcn_fence(__ATOMIC_ACQUIRE, "agent");
    }
    __syncthreads();
}

// ---------------------------------------------------------------------------
// fp32 -> bf16 cast (weights, Y0)
// ---------------------------------------------------------------------------
__global__ __launch_bounds__(256) void cast_bf(const float* __restrict__ in,
                                               short* __restrict__ out, int n) {
    int i = blockIdx.x * 256 + threadIdx.x;
    if (i < n) out[i] = (short)f2bf(in[i]);
}

// ---------------------------------------------------------------------------
// X (B,TIN,N) fp32 -> Xt (TIN,B,N) bf16
// ---------------------------------------------------------------------------
__global__ __launch_bounds__(256) void transpose_X_bf(const float* __restrict__ X,
                                                      short* __restrict__ Xt) {
    int idx = blockIdx.x * 256 + threadIdx.x;   // t*(B*N) + b*N + n
    int n = idx & (N_IN - 1);
    int b = (idx >> 8) & (B - 1);
    int t = idx >> 14;
    Xt[idx] = (short)f2bf(X[(b * TIN + t) * N_IN + n]);
}

// ===========================================================================
// ENCODER mega-kernel: per layer, per chunk: GI GEMM phase -> 8 GRU steps.
// grid = NB x 256. Barriers separate phases. Each block owns one (m,r) tile.
// ===========================================================================
struct EncArgs {
    const short* Xt;       // (TIN,B,N) bf16
    short* seqA;           // (TIN,B,M) bf16   layer-0 outputs
    float* gi;             // (CH,B,M3) fp32   chunk scratch
    const short* wih0; const short* whh0; const float* bih0; const float* bhh0;
    const short* wih1; const short* whh1; const float* bih1; const float* bhh1;
    float* h0f; float* h1f;
    short* h0b; short* h1b;      // ping-pong (2,B,M)
    unsigned* flags; unsigned* eps;
};

__global__ __launch_bounds__(256, 1) void enc_mega(EncArgs a) {
    __shared__ float lds[3][4][64][4];          // 12 KB
    const int bid  = blockIdx.x;
    const int wave = threadIdx.x >> 6;
    const int lane = threadIdx.x & 63;
    const int lrow = lane & 15;
    const int ko8  = (lane >> 4) * 8;
    unsigned epoch = 0;

    for (int layer = 0; layer < 2; ++layer) {
        const short* Wih = layer ? a.wih1 : a.wih0;
        const short* Whh = layer ? a.whh1 : a.whh0;
        const float* bih = layer ? a.bih1 : a.bih0;
        const float* bhh = layer ? a.bhh1 : a.bhh0;
        const short* inseq = layer ? a.seqA : a.Xt;
        const int K = layer ? M : N_IN;
        float* hf = layer ? a.h1f : a.h0f;
        short* hb = layer ? a.h1b : a.h0b;

        for (int c = 0; c < TIN / CH; ++c) {
            // ---- GI phase: gi[tt,b,:] = inseq[chunk] @ Wih^T + bih ----
            // 512 rows x 192 col-tiles = 6144 tiles over 1024 waves -> 6/wave
            {
                const short* A = inseq + (size_t)c * CH * B * K;
                int gw = bid * 4 + wave;               // 0..1023
                for (int i = 0; i < 6; ++i) {
                    int tile = gw * 6 + i;             // 0..6143
                    int r0 = (tile / 192) * 16;
                    int c0 = (tile % 192) * 16;
                    const short* ap = A + (size_t)(r0 + lrow) * K + ko8;
                    const short* wp = Wih + (size_t)(c0 + lrow) * K + ko8;
                    floatx4 acc = {0.f, 0.f, 0.f, 0.f};
                    #pragma unroll 4
                    for (int k = 0; k < K; k += 32) {
                        bf16x8 av = *(const bf16x8*)(ap + k);
                        bf16x8 bv = *(const bf16x8*)(wp + k);
                        acc = __builtin_amdgcn_mfma_f32_16x16x32_bf16(av, bv, acc, 0, 0, 0);
                    }
                    int col = c0 + lrow;
                    float bv = bih[col];
                    int rb = r0 + (lane >> 4) * 4;
                    #pragma unroll
                    for (int q = 0; q < 4; q++)
                        a.gi[(size_t)(rb + q) * M3 + col] = acc[q] + bv;
                }
            }
            gridbar(a.flags, a.eps, ++epoch, bid);
            // ---- 8 GRU steps; each block owns one (m,r) tile --------------
            for (int tt = 0; tt < CH; ++tt) {
                int t = c * CH + tt;
                int pin = t & 1, pout = pin ^ 1;
                const short* h_in = hb + (size_t)pin * B * M;
                const float* gi_t = a.gi + (size_t)tt * B * M3;
                int m0 = (bid >> 2) * 16;
                int r0 = (bid & 3) * 16;
                const int Kq = M >> 2;                 // 256
                const short* ap = h_in + (size_t)(r0 + lrow) * M + wave * Kq + ko8;
                const short* wr = Whh + (size_t)(m0 + lrow) * M + wave * Kq + ko8;
                const short* wz = wr + (size_t)M * M;
                const short* wn = wr + (size_t)2 * M * M;
                floatx4 ar = {0.f, 0.f, 0.f, 0.f};
                floatx4 az = {0.f, 0.f, 0.f, 0.f};
                floatx4 ah = {0.f, 0.f, 0.f, 0.f};
                #pragma unroll
                for (int k = 0; k < Kq; k += 32) {
                    bf16x8 av = *(const bf16x8*)(ap + k);
                    ar = __builtin_amdgcn_mfma_f32_16x16x32_bf16(av, *(const bf16x8*)(wr + k), ar, 0, 0, 0);
                    az = __builtin_amdgcn_mfma_f32_16x16x32_bf16(av, *(const bf16x8*)(wz + k), az, 0, 0, 0);
                    ah = __builtin_amdgcn_mfma_f32_16x16x32_bf16(av, *(const bf16x8*)(wn + k), ah, 0, 0, 0);
                }
                #pragma unroll
                for (int i = 0; i < 4; i++) {
                    lds[0][wave][lane][i] = ar[i];
                    lds[1][wave][lane][i] = az[i];
                    lds[2][wave][lane][i] = ah[i];
                }
                __syncthreads();
                int row = threadIdx.x >> 4, col = threadIdx.x & 15;
                int sl = (row >> 2) * 16 + col, rg = row & 3;
                float sr = lds[0][0][sl][rg] + lds[0][1][sl][rg] + lds[0][2][sl][rg] + lds[0][3][sl][rg];
                float sz = lds[1][0][sl][rg] + lds[1][1][sl][rg] + lds[1][2][sl][rg] + lds[1][3][sl][rg];
                float sn = lds[2][0][sl][rg] + lds[2][1][sl][rg] + lds[2][2][sl][rg] + lds[2][3][sl][rg];
                int b = r0 + row, m = m0 + col;
                const float* gir = gi_t + (size_t)b * M3;
                float r = sigm(gir[m] + sr + bhh[m]);
                float z = sigm(gir[M + m] + sz + bhh[M + m]);
                float n = tanhf(gir[2 * M + m] + r * (sn + bhh[2 * M + m]));
                size_t hi = (size_t)b * M + m;
                float hv = (1.f - z) * n + z * hf[hi];
                hf[hi] = hv;
                short hbv = (short)f2bf(hv);
                hb[(size_t)pout * B * M + hi] = hbv;
                if (layer == 0) a.seqA[(size_t)t * B * M + hi] = hbv;
                gridbar(a.flags, a.eps, ++epoch, bid);
            }
        }
    }
}

// ===========================================================================
// DECODER mega-kernel: 5 barrier-separated phases per step. grid = NB x 256.
// ===========================================================================
struct DecArgs {
    const short* yb;                         // (B,O) bf16 initial y
    const short* wih0; const short* whh0; const float* bih0; const float* bhh0;
    const short* wih1; const short* whh1; const float* bih1; const float* bhh1;
    const short* wfc1; const float* fc1b;
    const float* lng; const float* lnb;
    const short* wfc2; const float* fc2b;
    float* h0f; float* h1f;
    short* h0b; short* h1b;                  // ping-pong (2,B,M)
    float* zb;                               // (B,LM) fp32
    short* zbb;                              // (B,LM) bf16
    float* stats;                            // (TDEC,2,B) fp32, pre-zeroed
    float* out;                              // (B,TDEC,O) fp32 logits (output)
    unsigned* flags; unsigned* eps;
};

__global__ __launch_bounds__(256, 1) void dec_mega(DecArgs a) {
    __shared__ short xs[16 * O_DIM];         // 16 KB, XOR-swizzled A rows
    __shared__ float lds[4][4][64][4];       // 16 KB
    const int bid  = blockIdx.x;
    const int wave = threadIdx.x >> 6;
    const int lane = threadIdx.x & 63;
    const int lrow = lane & 15;
    const int ko8  = (lane >> 4) * 8;
    const int ldl  = TDEC * O_DIM;
    unsigned epoch = 0;

    for (int t = 0; t < TDEC; ++t) {
        int pin = t & 1, pout = pin ^ 1;
        int r0 = (bid & 3) * 16;
        int m0 = (bid >> 2) * 16;
        // ============ Phase A: gru0 + fused softmax(prev logits) ===========
        {
            int rr = wave * 4 + (lane >> 4);       // row 0..15 of this block
            int cl = lane & 15;
            if (t > 0) {
                const float* rowp = a.out + (size_t)(r0 + rr) * ldl
                                  + (size_t)(t - 1) * O_DIM + cl * 32;
                float v[32];
                float mx = -3.4e38f;
                #pragma unroll
                for (int j = 0; j < 32; j++) { v[j] = rowp[j]; mx = fmaxf(mx, v[j]); }
                #pragma unroll
                for (int off = 1; off < 16; off <<= 1) mx = fmaxf(mx, __shfl_xor(mx, off, 16));
                float s = 0.f;
                #pragma unroll
                for (int j = 0; j < 32; j++) { v[j] = __expf(v[j] - mx); s += v[j]; }
                #pragma unroll
                for (int off = 1; off < 16; off <<= 1) s += __shfl_xor(s, off, 16);
                float inv = 1.f / s;
                #pragma unroll
                for (int j = 0; j < 32; j += 2) {
                    unsigned int pk = (unsigned int)f2bf(v[j] * inv)
                                    | ((unsigned int)f2bf(v[j + 1] * inv) << 16);
                    int byte = ((rr * O_DIM + cl * 32 + j) * 2) ^ ((rr & 7) << 4);
                    *(unsigned int*)((char*)xs + byte) = pk;
                }
            } else {
                const short* rowp = a.yb + (size_t)(r0 + rr) * O_DIM + cl * 32;
                #pragma unroll
                for (int j = 0; j < 32; j += 2) {
                    unsigned int pk = (unsigned int)(unsigned short)rowp[j]
                                    | ((unsigned int)(unsigned short)rowp[j + 1] << 16);
                    int byte = ((rr * O_DIM + cl * 32 + j) * 2) ^ ((rr & 7) << 4);
                    *(unsigned int*)((char*)xs + byte) = pk;
                }
            }
            __syncthreads();
            const int KqI = O_DIM >> 2;            // 128
            const int KqH = M >> 2;                // 256
            const short* wrI = a.wih0 + (size_t)(m0 + lrow) * O_DIM + wave * KqI + ko8;
            const short* wzI = wrI + (size_t)M * O_DIM;
            const short* wnI = wrI + (size_t)2 * M * O_DIM;
            const short* wrH = a.whh0 + (size_t)(m0 + lrow) * M + wave * KqH + ko8;
            const short* wzH = wrH + (size_t)M * M;
            const short* wnH = wrH + (size_t)2 * M * M;
            floatx4 ar = {0.f, 0.f, 0.f, 0.f};
            floatx4 az = {0.f, 0.f, 0.f, 0.f};
            floatx4 ai = {0.f, 0.f, 0.f, 0.f};
            floatx4 ah = {0.f, 0.f, 0.f, 0.f};
            #pragma unroll
            for (int k = 0; k < KqI; k += 32) {
                int abyte = ((lrow * O_DIM + wave * KqI + ko8 + k) * 2) ^ ((lrow & 7) << 4);
                bf16x8 av = *(const bf16x8*)((const char*)xs + abyte);
                ar = __builtin_amdgcn_mfma_f32_16x16x32_bf16(av, *(const bf16x8*)(wrI + k), ar, 0, 0, 0);
                az = __builtin_amdgcn_mfma_f32_16x16x32_bf16(av, *(const bf16x8*)(wzI + k), az, 0, 0, 0);
                ai = __builtin_amdgcn_mfma_f32_16x16x32_bf16(av, *(const bf16x8*)(wnI + k), ai, 0, 0, 0);
            }
            const short* apH = a.h0b + (size_t)pin * B * M + (size_t)(r0 + lrow) * M + wave * KqH + ko8;
            #pragma unroll
            for (int k = 0; k < KqH; k += 32) {
                bf16x8 av = *(const bf16x8*)(apH + k);
                ar = __builtin_amdgcn_mfma_f32_16x16x32_bf16(av, *(const bf16x8*)(wrH + k), ar, 0, 0, 0);
                az = __builtin_amdgcn_mfma_f32_16x16x32_bf16(av, *(const bf16x8*)(wzH + k), az, 0, 0, 0);
                ah = __builtin_amdgcn_mfma_f32_16x16x32_bf16(av, *(const bf16x8*)(wnH + k), ah, 0, 0, 0);
            }
            #pragma unroll
            for (int i = 0; i < 4; i++) {
                lds[0][wave][lane][i] = ar[i];
                lds[1][wave][lane][i] = az[i];
                lds[2][wave][lane][i] = ai[i];
                lds[3][wave][lane][i] = ah[i];
            }
            __syncthreads();
            int row = threadIdx.x >> 4, col = threadIdx.x & 15;
            int sl = (row >> 2) * 16 + col, rg = row & 3;
            float sr = lds[0][0][sl][rg] + lds[0][1][sl][rg] + lds[0][2][sl][rg] + lds[0][3][sl][rg];
            float sz = lds[1][0][sl][rg] + lds[1][1][sl][rg] + lds[1][2][sl][rg] + lds[1][3][sl][rg];
            float si = lds[2][0][sl][rg] + lds[2][1][sl][rg] + lds[2][2][sl][rg] + lds[2][3][sl][rg];
            float sh = lds[3][0][sl][rg] + lds[3][1][sl][rg] + lds[3][2][sl][rg] + lds[3][3][sl][rg];
            int b = r0 + row, m = m0 + col;
            float r = sigm(sr + a.bih0[m] + a.bhh0[m]);
            float z = sigm(sz + a.bih0[M + m] + a.bhh0[M + m]);
            float n = tanhf(si + a.bih0[2 * M + m] + r * (sh + a.bhh0[2 * M + m]));
            size_t hi = (size_t)b * M + m;
            float hv = (1.f - z) * n + z * a.h0f[hi];
            a.h0f[hi] = hv;
            a.h0b[(size_t)pout * B * M + hi] = (short)f2bf(hv);
        }
        gridbar(a.flags, a.eps, ++epoch, bid);
        // ============ Phase B: gru1 (x = new h0, Kx = M) ===================
        {
            const int Kq = M >> 2;
            const short* wrI = a.wih1 + (size_t)(m0 + lrow) * M + wave * Kq + ko8;
            const short* wzI = wrI + (size_t)M * M;
            const short* wnI = wrI + (size_t)2 * M * M;
            const short* wrH = a.whh1 + (size_t)(m0 + lrow) * M + wave * Kq + ko8;
            const short* wzH = wrH + (size_t)M * M;
            const short* wnH = wrH + (size_t)2 * M * M;
            floatx4 ar = {0.f, 0.f, 0.f, 0.f};
            floatx4 az = {0.f, 0.f, 0.f, 0.f};
            floatx4 ai = {0.f, 0.f, 0.f, 0.f};
            floatx4 ah = {0.f, 0.f, 0.f, 0.f};
            const short* apI = a.h0b + (size_t)pout * B * M + (size_t)(r0 + lrow) * M + wave * Kq + ko8;
            #pragma unroll
            for (int k = 0; k < Kq; k += 32) {
                bf16x8 av = *(const bf16x8*)(apI + k);
                ar = __builtin_amdgcn_mfma_f32_16x16x32_bf16(av, *(const bf16x8*)(wrI + k), ar, 0, 0, 0);
                az = __builtin_amdgcn_mfma_f32_16x16x32_bf16(av, *(const bf16x8*)(wzI + k), az, 0, 0, 0);
                ai = __builtin_amdgcn_mfma_f32_16x16x32_bf16(av, *(const bf16x8*)(wnI + k), ai, 0, 0, 0);
            }
            const short* apH = a.h1b + (size_t)pin * B * M + (size_t)(r0 + lrow) * M + wave * Kq + ko8;
            #pragma unroll
            for (int k = 0; k < Kq; k += 32) {
                bf16x8 av = *(const bf16x8*)(apH + k);
                ar = __builtin_amdgcn_mfma_f32_16x16x32_bf16(av, *(const bf16x8*)(wrH + k), ar, 0, 0, 0);
                az = __builtin_amdgcn_mfma_f32_16x16x32_bf16(av, *(const bf16x8*)(wzH + k), az, 0, 0, 0);
                ah = __builtin_amdgcn_mfma_f32_16x16x32_bf16(av, *(const bf16x8*)(wnH + k), ah, 0, 0, 0);
            }
            #pragma unroll
            for (int i = 0; i < 4; i++) {
                lds[0][wave][lane][i] = ar[i];
                lds[1][wave][lane][i] = az[i];
                lds[2][wave][lane][i] = ai[i];
                lds[3][wave][lane][i] = ah[i];
            }
            __syncthreads();
            int row = threadIdx.x >> 4, col = threadIdx.x & 15;
            int sl = (row >> 2) * 16 + col, rg = row & 3;
            float sr = lds[0][0][sl][rg] + lds[0][1][sl][rg] + lds[0][2][sl][rg] + lds[0][3][sl][rg];
            float sz = lds[1][0][sl][rg] + lds[1][1][sl][rg] + lds[1][2][sl][rg] + lds[1][3][sl][rg];
            float si = lds[2][0][sl][rg] + lds[2][1][sl][rg] + lds[2][2][sl][rg] + lds[2][3][sl][rg];
            float sh = lds[3][0][sl][rg] + lds[3][1][sl][rg] + lds[3][2][sl][rg] + lds[3][3][sl][rg];
            int b = r0 + row, m = m0 + col;
            float r = sigm(sr + a.bih1[m] + a.bhh1[m]);
            float z = sigm(sz + a.bih1[M + m] + a.bhh1[M + m]);
            float n = tanhf(si + a.bih1[2 * M + m] + r * (sh + a.bhh1[2 * M + m]));
            size_t hi = (size_t)b * M + m;
            float hv = (1.f - z) * n + z * a.h1f[hi];
            a.h1f[hi] = hv;
            a.h1b[(size_t)pout * B * M + hi] = (short)f2bf(hv);
        }
        gridbar(a.flags, a.eps, ++epoch, bid);
        // ============ Phase C: fc1 (2 col-tiles/block) + LN stats ==========
        {
            float* st = a.stats + (size_t)t * 2 * B;
            const int Kq = M >> 2;
            const short* ap = a.h1b + (size_t)pout * B * M + (size_t)(r0 + lrow) * M + wave * Kq + ko8;
            const short* wp[2];
            floatx4 acc[2];
            #pragma unroll
            for (int j = 0; j < 2; ++j) {
                int c0 = (j * 64 + (bid >> 2)) * 16;
                wp[j] = a.wfc1 + (size_t)(c0 + lrow) * M + wave * Kq + ko8;
                acc[j] = (floatx4){0.f, 0.f, 0.f, 0.f};
            }
            #pragma unroll
            for (int k = 0; k < Kq; k += 32) {
                bf16x8 av = *(const bf16x8*)(ap + k);
                #pragma unroll
                for (int j = 0; j < 2; ++j)
                    acc[j] = __builtin_amdgcn_mfma_f32_16x16x32_bf16(av, *(const bf16x8*)(wp[j] + k), acc[j], 0, 0, 0);
            }
            #pragma unroll
            for (int j = 0; j < 2; ++j)
                #pragma unroll
                for (int i = 0; i < 4; i++) lds[j][wave][lane][i] = acc[j][i];
            __syncthreads();
            int row = threadIdx.x >> 4, col = threadIdx.x & 15;
            int sl = (row >> 2) * 16 + col, rg = row & 3;
            #pragma unroll
            for (int j = 0; j < 2; ++j) {
                int c0 = (j * 64 + (bid >> 2)) * 16;
                float s = lds[j][0][sl][rg] + lds[j][1][sl][rg]
                        + lds[j][2][sl][rg] + lds[j][3][sl][rg];
                float val = s + a.fc1b[c0 + col];
                a.zb[(size_t)(r0 + row) * LM + c0 + col] = val;
                float sv = val, sq = val * val;
                #pragma unroll
                for (int off = 1; off < 16; off <<= 1) {
                    sv += __shfl_xor(sv, off, 16);
                    sq += __shfl_xor(sq, off, 16);
                }
                if ((threadIdx.x & 15) == 0) {
                    atomicAdd(&st[r0 + row], sv);
                    atomicAdd(&st[B + r0 + row], sq);
                }
            }
        }
        gridbar(a.flags, a.eps, ++epoch, bid);
        // ============ Phase D: LN + GELU apply (2 elems/thread) ============
        {
            const float* st = a.stats + (size_t)t * 2 * B;
            int e0 = (bid * 256 + threadIdx.x) * 2;      // B*LM = 131072
            int rowd = e0 >> 11;
            float mu = st[rowd] * (1.f / LM);
            float var = st[B + rowd] * (1.f / LM) - mu * mu;
            float inv = rsqrtf(var + 1e-5f);
            #pragma unroll
            for (int j = 0; j < 2; j++) {
                int e = e0 + j;
                int cc = e & (LM - 1);
                float zn = (a.zb[e] - mu) * inv * a.lng[cc] + a.lnb[cc];
                float ge = 0.5f * zn * (1.f + erff(zn * 0.70710678118654752f));
                a.zbb[e] = (short)f2bf(ge);
            }
        }
        gridbar(a.flags, a.eps, ++epoch, bid);
        // ============ Phase E: fc2 -> logits out[:, t, :] ==================
        if (bid < 128) {
            int c0 = (bid >> 2) * 16;
            const int Kq = LM >> 2;                      // 512
            const short* ap = a.zbb + (size_t)(r0 + lrow) * LM + wave * Kq + ko8;
            const short* wpp = a.wfc2 + (size_t)(c0 + lrow) * LM + wave * Kq + ko8;
            floatx4 acc = {0.f, 0.f, 0.f, 0.f};
            #pragma unroll 4
            for (int k = 0; k < Kq; k += 32) {
                bf16x8 av = *(const bf16x8*)(ap + k);
                bf16x8 bv = *(const bf16x8*)(wpp + k);
                acc = __builtin_amdgcn_mfma_f32_16x16x32_bf16(av, bv, acc, 0, 0, 0);
            }
            #pragma unroll
            for (int i = 0; i < 4; i++) lds[0][wave][lane][i] = acc[i];
            __syncthreads();
            int row = threadIdx.x >> 4, col = threadIdx.x & 15;
            int sl = (row >> 2) * 16 + col, rg = row & 3;
            float s = lds[0][0][sl][rg] + lds[0][1][sl][rg]
                    + lds[0][2][sl][rg] + lds[0][3][sl][rg];
            a.out[(size_t)(r0 + row) * ldl + (size_t)t * O_DIM + c0 + col]
                = s + a.fc2b[c0 + col];
        }
        gridbar(a.flags, a.eps, ++epoch, bid);
    }
}

// ===========================================================================
extern "C" void kernel_launch(void* const* d_in, const int* in_sizes, int n_in,
                              void* d_out, int out_size, void* d_ws, size_t ws_size,
                              hipStream_t stream) {
    const float* X        = (const float*)d_in[0];
    const float* Y0       = (const float*)d_in[1];
    const float* enc_Wih0 = (const float*)d_in[2];
    const float* enc_Whh0 = (const float*)d_in[3];
    const float* enc_bih0 = (const float*)d_in[4];
    const float* enc_bhh0 = (const float*)d_in[5];
    const float* enc_Wih1 = (const float*)d_in[6];
    const float* enc_Whh1 = (const float*)d_in[7];
    const float* enc_bih1 = (const float*)d_in[8];
    const float* enc_bhh1 = (const float*)d_in[9];
    const float* dec_Wih0 = (const float*)d_in[10];
    const float* dec_Whh0 = (const float*)d_in[11];
    const float* dec_bih0 = (const float*)d_in[12];
    const float* dec_bhh0 = (const float*)d_in[13];
    const float* dec_Wih1 = (const float*)d_in[14];
    const float* dec_Whh1 = (const float*)d_in[15];
    const float* dec_bih1 = (const float*)d_in[16];
    const float* dec_bhh1 = (const float*)d_in[17];
    const float* fc1_w    = (const float*)d_in[18];
    const float* fc1_b    = (const float*)d_in[19];
    const float* ln_g     = (const float*)d_in[20];
    const float* ln_b     = (const float*)d_in[21];
    const float* fc2_w    = (const float*)d_in[22];
    const float* fc2_b    = (const float*)d_in[23];
    float* out = (float*)d_out;

    // ---- workspace carve-up ----
    char* p = (char*)d_ws;
    auto carve = [&](size_t bytes) {
        void* r = p;
        p += (bytes + 255) & ~(size_t)255;
        return r;
    };
    short* Xt    = (short*)carve((size_t)TIN * B * N_IN * 2);
    short* seqA  = (short*)carve((size_t)TIN * B * M * 2);
    float* gi_ch = (float*)carve((size_t)CH * B * M3 * 4);
    short* we_ih0 = (short*)carve((size_t)M3 * N_IN * 2);
    short* we_hh0 = (short*)carve((size_t)M3 * M * 2);
    short* we_ih1 = (short*)carve((size_t)M3 * M * 2);
    short* we_hh1 = (short*)carve((size_t)M3 * M * 2);
    short* wd_ih0 = (short*)carve((size_t)M3 * O_DIM * 2);
    short* wd_hh0 = (short*)carve((size_t)M3 * M * 2);
    short* wd_ih1 = (short*)carve((size_t)M3 * M * 2);
    short* wd_hh1 = (short*)carve((size_t)M3 * M * 2);
    short* wfc1   = (short*)carve((size_t)LM * M * 2);
    short* wfc2   = (short*)carve((size_t)O_DIM * LM * 2);
    float* h0f = (float*)carve((size_t)B * M * 4);
    float* h1f = (float*)carve((size_t)B * M * 4);
    short* h0b = (short*)carve((size_t)2 * B * M * 2);   // ping-pong
    short* h1b = (short*)carve((size_t)2 * B * M * 2);
    short* yb  = (short*)carve((size_t)B * O_DIM * 2);
    float* zb  = (float*)carve((size_t)B * LM * 4);
    short* zbb = (short*)carve((size_t)B * LM * 2);
    float* lnstats = (float*)carve((size_t)TDEC * 2 * B * 4);
    unsigned* eflags = (unsigned*)carve((size_t)NB * 32 * 4);  // padded flags
    unsigned* eeps   = (unsigned*)carve(256);
    unsigned* dflags = (unsigned*)carve((size_t)NB * 32 * 4);
    unsigned* deps   = (unsigned*)carve(256);

    auto cast = [&](const float* src, short* dst, int n) {
        cast_bf<<<(n + 255) / 256, 256, 0, stream>>>(src, dst, n);
    };
    cast(enc_Wih0, we_ih0, M3 * N_IN);
    cast(enc_Whh0, we_hh0, M3 * M);
    cast(enc_Wih1, we_ih1, M3 * M);
    cast(enc_Whh1, we_hh1, M3 * M);
    cast(dec_Wih0, wd_ih0, M3 * O_DIM);
    cast(dec_Whh0, wd_hh0, M3 * M);
    cast(dec_Wih1, wd_ih1, M3 * M);
    cast(dec_Whh1, wd_hh1, M3 * M);
    cast(fc1_w, wfc1, LM * M);
    cast(fc2_w, wfc2, O_DIM * LM);
    cast(Y0, yb, B * O_DIM);
    transpose_X_bf<<<(TIN * B * N_IN) / 256, 256, 0, stream>>>(X, Xt);

    hipMemsetAsync(h0f, 0, (size_t)B * M * 4, stream);
    hipMemsetAsync(h1f, 0, (size_t)B * M * 4, stream);
    hipMemsetAsync(h0b, 0, (size_t)B * M * 2, stream);   // parity-0 buffer
    hipMemsetAsync(h1b, 0, (size_t)B * M * 2, stream);
    hipMemsetAsync(lnstats, 0, (size_t)TDEC * 2 * B * 4, stream);
    hipMemsetAsync(eflags, 0, (size_t)NB * 32 * 4, stream);
    hipMemsetAsync(eeps, 0, 256, stream);
    hipMemsetAsync(dflags, 0, (size_t)NB * 32 * 4, stream);
    hipMemsetAsync(deps, 0, 256, stream);

    // -------------------- encoder (one mega-kernel) -----------------------
    EncArgs ea;
    ea.Xt = Xt; ea.seqA = seqA; ea.gi = gi_ch;
    ea.wih0 = we_ih0; ea.whh0 = we_hh0; ea.bih0 = enc_bih0; ea.bhh0 = enc_bhh0;
    ea.wih1 = we_ih1; ea.whh1 = we_hh1; ea.bih1 = enc_bih1; ea.bhh1 = enc_bhh1;
    ea.h0f = h0f; ea.h1f = h1f; ea.h0b = h0b; ea.h1b = h1b;
    ea.flags = eflags; ea.eps = eeps;
    enc_mega<<<dim3(NB), dim3(256), 0, stream>>>(ea);

    // -------------------- decoder (one mega-kernel) -----------------------
    DecArgs da;
    da.yb = yb;
    da.wih0 = wd_ih0; da.whh0 = wd_hh0; da.bih0 = dec_bih0; da.bhh0 = dec_bhh0;
    da.wih1 = wd_ih1; da.whh1 = wd_hh1; da.bih1 = dec_bih1; da.bhh1 = dec_bhh1;
    da.wfc1 = wfc1; da.fc1b = fc1_b;
    da.lng = ln_g; da.lnb = ln_b;
    da.wfc2 = wfc2; da.fc2b = fc2_b;
    da.h0f = h0f; da.h1f = h1f; da.h0b = h0b; da.h1b = h1b;
    da.zb = zb; da.zbb = zbb; da.stats = lnstats; da.out = out;
    da.flags = dflags; da.eps = deps;
    dec_mega<<<dim3(NB), dim3(256), 0, stream>>>(da);
}

// Round 6
// 7614.637 us; speedup vs baseline: 1.9107x; 1.4533x over previous
//
#include <hip/hip_runtime.h>
#include <math.h>

#define B 64
#define TIN 128
#define N_IN 256
#define M 1024
#define O_DIM 512
#define LM 2048
#define TDEC 64
#define M3 3072
#define CH 8     // encoder gi timestep chunk
#define NB 256   // grid blocks for the two mega-kernels (1 block/CU)

typedef short bf16x8 __attribute__((ext_vector_type(8)));
typedef float floatx4 __attribute__((ext_vector_type(4)));
typedef unsigned long long u64_t;

__device__ __forceinline__ unsigned short f2bf(float f) {
    unsigned int u = __float_as_uint(f);
    u += 0x7FFFu + ((u >> 16) & 1u);      // round-to-nearest-even
    return (unsigned short)(u >> 16);
}
__device__ __forceinline__ float sigm(float x) { return 1.f / (1.f + expf(-x)); }

// ---- relaxed agent-scope accessors: per-access MALL coherence, NO fences ----
__device__ __forceinline__ float ald_f(const float* p) {
    return __hip_atomic_load((float*)p, __ATOMIC_RELAXED, __HIP_MEMORY_SCOPE_AGENT);
}
__device__ __forceinline__ void ast_f(float* p, float v) {
    __hip_atomic_store(p, v, __ATOMIC_RELAXED, __HIP_MEMORY_SCOPE_AGENT);
}
__device__ __forceinline__ void ast_u(unsigned* p, unsigned v) {
    __hip_atomic_store(p, v, __ATOMIC_RELAXED, __HIP_MEMORY_SCOPE_AGENT);
}
__device__ __forceinline__ bf16x8 ald_b8(const short* p) {
    u64_t lo = __hip_atomic_load((u64_t*)p, __ATOMIC_RELAXED, __HIP_MEMORY_SCOPE_AGENT);
    u64_t hi = __hip_atomic_load((u64_t*)(p + 4), __ATOMIC_RELAXED, __HIP_MEMORY_SCOPE_AGENT);
    union { u64_t q[2]; bf16x8 v; } u;
    u.q[0] = lo; u.q[1] = hi;
    return u.v;
}
// pack (even,odd) col pair to one u32 atomic store; all threads call, even store
__device__ __forceinline__ void ast_h_pair(short* addr_even, float hv) {
    unsigned short hb16 = f2bf(hv);
    int partner = __shfl_xor((int)hb16, 1, 64);
    if ((threadIdx.x & 1) == 0) {
        unsigned pair = (unsigned)hb16 | ((unsigned)(unsigned short)partner << 16);
        __hip_atomic_store((unsigned*)addr_even, pair,
                           __ATOMIC_RELAXED, __HIP_MEMORY_SCOPE_AGENT);
    }
}

// ---------------------------------------------------------------------------
// Fence-free grid barrier. __syncthreads() drains vmcnt for all waves
// (compiler emits full s_waitcnt before s_barrier), so all prior agent-atomic
// writes are at the MALL before the flag store. Root (bid 0) polls all 256
// padded flags with one thread each; 8 relays (bid 1..7 + root) fan the epoch
// out so each broadcast line has <=32 pollers. Relaxed atomics only: no
// buffer_inv / buffer_wbl2, L2 stays warm. Bounded spins as escape hatches.
// ---------------------------------------------------------------------------
__device__ __forceinline__ void gridbar(unsigned* flags, unsigned* eps,
                                        unsigned* relay, unsigned epoch, int bid) {
    __syncthreads();
    if (bid == 0) {
        if (threadIdx.x == 0)
            __hip_atomic_store(&flags[0], epoch, __ATOMIC_RELAXED,
                               __HIP_MEMORY_SCOPE_AGENT);
        unsigned g = 0;
        while (__hip_atomic_load(&flags[(size_t)threadIdx.x * 32],
                                 __ATOMIC_RELAXED, __HIP_MEMORY_SCOPE_AGENT) < epoch) {
            __builtin_amdgcn_s_sleep(1);
            if (++g > (1u << 22)) break;
        }
        __syncthreads();
        if (threadIdx.x == 0) {
            __hip_atomic_store(eps, epoch, __ATOMIC_RELAXED,
                               __HIP_MEMORY_SCOPE_AGENT);
            __hip_atomic_store(&relay[0], epoch, __ATOMIC_RELAXED,
                               __HIP_MEMORY_SCOPE_AGENT);
        }
    } else if (threadIdx.x == 0) {
        __hip_atomic_store(&flags[(size_t)bid * 32], epoch, __ATOMIC_RELAXED,
                           __HIP_MEMORY_SCOPE_AGENT);
        unsigned g = 0;
        if (bid < 8) {
            while (__hip_atomic_load(eps, __ATOMIC_RELAXED,
                                     __HIP_MEMORY_SCOPE_AGENT) < epoch) {
                __builtin_amdgcn_s_sleep(1);
                if (++g > (1u << 22)) break;
            }
            __hip_atomic_store(&relay[(size_t)bid * 32], epoch, __ATOMIC_RELAXED,
                               __HIP_MEMORY_SCOPE_AGENT);
        } else {
            unsigned* rl = &relay[(size_t)(bid & 7) * 32];
            while (__hip_atomic_load(rl, __ATOMIC_RELAXED,
                                     __HIP_MEMORY_SCOPE_AGENT) < epoch) {
                __builtin_amdgcn_s_sleep(1);
                if (++g > (1u << 22)) break;
            }
        }
    }
    __syncthreads();
}

// ---------------------------------------------------------------------------
// fp32 -> bf16 cast (weights, Y0)
// ---------------------------------------------------------------------------
__global__ __launch_bounds__(256) void cast_bf(const float* __restrict__ in,
                                               short* __restrict__ out, int n) {
    int i = blockIdx.x * 256 + threadIdx.x;
    if (i < n) out[i] = (short)f2bf(in[i]);
}

// ---------------------------------------------------------------------------
// X (B,TIN,N) fp32 -> Xt (TIN,B,N) bf16
// ---------------------------------------------------------------------------
__global__ __launch_bounds__(256) void transpose_X_bf(const float* __restrict__ X,
                                                      short* __restrict__ Xt) {
    int idx = blockIdx.x * 256 + threadIdx.x;   // t*(B*N) + b*N + n
    int n = idx & (N_IN - 1);
    int b = (idx >> 8) & (B - 1);
    int t = idx >> 14;
    Xt[idx] = (short)f2bf(X[(b * TIN + t) * N_IN + n]);
}

// ===========================================================================
// ENCODER mega-kernel. XCD-aware ownership; weights via normal cached loads
// (L2-resident), cross-block state via agent atomics. seqA uses normal
// loads/stores with ONE fenced barrier at the layer0->layer1 transition.
// ===========================================================================
struct EncArgs {
    const short* Xt;       // (TIN,B,N) bf16
    short* seqA;           // (TIN,B,M) bf16   layer-0 outputs (normal access)
    float* gi;             // (CH,B,M3) fp32   chunk scratch (atomic access)
    const short* wih0; const short* whh0; const float* bih0; const float* bhh0;
    const short* wih1; const short* whh1; const float* bih1; const float* bhh1;
    float* h0f; float* h1f;
    short* h0b; short* h1b;      // ping-pong (2,B,M), atomic access
    unsigned* flags; unsigned* eps; unsigned* relay;
};

__global__ __launch_bounds__(256, 1) void enc_mega(EncArgs a) {
    __shared__ float lds[3][4][64][4];          // 12 KB
    const int bid  = blockIdx.x;
    const int wave = threadIdx.x >> 6;
    const int lane = threadIdx.x & 63;
    const int lrow = lane & 15;
    const int ko8  = (lane >> 4) * 8;
    unsigned epoch = 0;

    for (int layer = 0; layer < 2; ++layer) {
        const short* Wih = layer ? a.wih1 : a.wih0;
        const short* Whh = layer ? a.whh1 : a.whh0;
        const float* bih = layer ? a.bih1 : a.bih0;
        const float* bhh = layer ? a.bhh1 : a.bhh0;
        const short* inseq = layer ? a.seqA : a.Xt;
        const int K = layer ? M : N_IN;
        float* hf = layer ? a.h1f : a.h0f;
        short* hb = layer ? a.h1b : a.h0b;

        for (int c = 0; c < TIN / CH; ++c) {
            // ---- GI phase: gi[tt,b,:] = inseq[chunk] @ Wih^T + bih ----
            // XCD-grouped: each XCD owns 24 col-tiles for all 32 row-tiles,
            // so each weight col-panel lives in exactly one L2.
            {
                const short* A = inseq + (size_t)c * CH * B * K;
                int xcd = bid & 7;
                int l   = bid >> 3;                    // 0..31
                int w4  = l * 4 + wave;                // 0..127
                for (int i = 0; i < 6; ++i) {
                    int gt   = w4 * 6 + i;             // 0..767
                    int colt = xcd * 24 + (gt % 24);   // 0..191
                    int rowt = gt / 24;                // 0..31
                    int r0 = rowt * 16;
                    int c0 = colt * 16;
                    const short* ap = A + (size_t)(r0 + lrow) * K + ko8;
                    const short* wp = Wih + (size_t)(c0 + lrow) * K + ko8;
                    floatx4 acc = {0.f, 0.f, 0.f, 0.f};
                    #pragma unroll 4
                    for (int k = 0; k < K; k += 32) {
                        bf16x8 av = *(const bf16x8*)(ap + k);   // normal (Xt/seqA)
                        bf16x8 bv = *(const bf16x8*)(wp + k);
                        acc = __builtin_amdgcn_mfma_f32_16x16x32_bf16(av, bv, acc, 0, 0, 0);
                    }
                    int col = c0 + lrow;
                    float bv = bih[col];
                    int rb = r0 + (lane >> 4) * 4;
                    #pragma unroll
                    for (int q = 0; q < 4; q++)
                        ast_f(&a.gi[(size_t)(rb + q) * M3 + col], acc[q] + bv);
                }
            }
            gridbar(a.flags, a.eps, a.relay, ++epoch, bid);
            // ---- 8 GRU steps; block owns (m-tile = bid&63, r-tile = bid>>6)
            for (int tt = 0; tt < CH; ++tt) {
                int t = c * CH + tt;
                int pin = t & 1, pout = pin ^ 1;
                const short* h_in = hb + (size_t)pin * B * M;
                float* gi_t = a.gi + (size_t)tt * B * M3;
                int m0 = (bid & 63) * 16;
                int r0 = (bid >> 6) * 16;
                const int Kq = M >> 2;                 // 256
                const short* ap = h_in + (size_t)(r0 + lrow) * M + wave * Kq + ko8;
                const short* wr = Whh + (size_t)(m0 + lrow) * M + wave * Kq + ko8;
                const short* wz = wr + (size_t)M * M;
                const short* wn = wr + (size_t)2 * M * M;
                floatx4 ar = {0.f, 0.f, 0.f, 0.f};
                floatx4 az = {0.f, 0.f, 0.f, 0.f};
                floatx4 ah = {0.f, 0.f, 0.f, 0.f};
                #pragma unroll
                for (int k = 0; k < Kq; k += 32) {
                    bf16x8 av = ald_b8(ap + k);        // cross-block state
                    ar = __builtin_amdgcn_mfma_f32_16x16x32_bf16(av, *(const bf16x8*)(wr + k), ar, 0, 0, 0);
                    az = __builtin_amdgcn_mfma_f32_16x16x32_bf16(av, *(const bf16x8*)(wz + k), az, 0, 0, 0);
                    ah = __builtin_amdgcn_mfma_f32_16x16x32_bf16(av, *(const bf16x8*)(wn + k), ah, 0, 0, 0);
                }
                #pragma unroll
                for (int i = 0; i < 4; i++) {
                    lds[0][wave][lane][i] = ar[i];
                    lds[1][wave][lane][i] = az[i];
                    lds[2][wave][lane][i] = ah[i];
                }
                __syncthreads();
                int row = threadIdx.x >> 4, col = threadIdx.x & 15;
                int sl = (row >> 2) * 16 + col, rg = row & 3;
                float sr = lds[0][0][sl][rg] + lds[0][1][sl][rg] + lds[0][2][sl][rg] + lds[0][3][sl][rg];
                float sz = lds[1][0][sl][rg] + lds[1][1][sl][rg] + lds[1][2][sl][rg] + lds[1][3][sl][rg];
                float sn = lds[2][0][sl][rg] + lds[2][1][sl][rg] + lds[2][2][sl][rg] + lds[2][3][sl][rg];
                int b = r0 + row, m = m0 + col;
                float gr = ald_f(&gi_t[(size_t)b * M3 + m]);
                float gz = ald_f(&gi_t[(size_t)b * M3 + M + m]);
                float gn = ald_f(&gi_t[(size_t)b * M3 + 2 * M + m]);
                float r = sigm(gr + sr + bhh[m]);
                float z = sigm(gz + sz + bhh[M + m]);
                float n = tanhf(gn + r * (sn + bhh[2 * M + m]));
                size_t hi = (size_t)b * M + m;
                float hv = (1.f - z) * n + z * hf[hi];   // hf block-private
                hf[hi] = hv;
                if (layer == 0) a.seqA[(size_t)t * B * M + hi] = (short)f2bf(hv);
                ast_h_pair(hb + (size_t)pout * B * M + (size_t)b * M + (m & ~1),
                           hv);
                gridbar(a.flags, a.eps, a.relay, ++epoch, bid);
            }
        }
        if (layer == 0) {
            // one fenced barrier: flush dirty seqA lines from every L2 and
            // invalidate, so layer-1 GI can read seqA with normal cached loads
            __builtin_amdgcn_fence(__ATOMIC_RELEASE, "agent");
            gridbar(a.flags, a.eps, a.relay, ++epoch, bid);
            __builtin_amdgcn_fence(__ATOMIC_ACQUIRE, "agent");
        }
    }
}

// ===========================================================================
// DECODER mega-kernel: 5 fence-free-barrier-separated phases per step.
// XCD-aware ownership keeps each weight panel in exactly one L2.
// ===========================================================================
struct DecArgs {
    const short* yb;                         // (B,O) bf16 initial y (normal)
    const short* wih0; const short* whh0; const float* bih0; const float* bhh0;
    const short* wih1; const short* whh1; const float* bih1; const float* bhh1;
    const short* wfc1; const float* fc1b;
    const float* lng; const float* lnb;
    const short* wfc2; const float* fc2b;
    float* h0f; float* h1f;                  // block-private fp32 state
    short* h0b; short* h1b;                  // ping-pong (2,B,M), atomic
    float* zb;                               // (B,LM) fp32, atomic
    short* zbb;                              // (B,LM) bf16, atomic
    float* stats;                            // (TDEC,2,B) fp32, atomicAdd
    float* out;                              // (B,TDEC,O) fp32 logits, atomic
    unsigned* flags; unsigned* eps; unsigned* relay;
};

__global__ __launch_bounds__(256, 1) void dec_mega(DecArgs a) {
    __shared__ short xs[16 * O_DIM];         // 16 KB, XOR-swizzled A rows
    __shared__ float lds[4][4][64][4];       // 16 KB
    const int bid  = blockIdx.x;
    const int wave = threadIdx.x >> 6;
    const int lane = threadIdx.x & 63;
    const int lrow = lane & 15;
    const int ko8  = (lane >> 4) * 8;
    const int ldl  = TDEC * O_DIM;
    unsigned epoch = 0;

    for (int t = 0; t < TDEC; ++t) {
        int pin = t & 1, pout = pin ^ 1;
        int m0 = (bid & 63) * 16;            // XCD-aware: bid%8 constant per m0
        int r0 = (bid >> 6) * 16;
        // ============ Phase A: gru0 + fused softmax(prev logits) ===========
        {
            int rr = wave * 4 + (lane >> 4);       // row 0..15 of this block
            int cl = lane & 15;
            if (t > 0) {
                const float* rowp = a.out + (size_t)(r0 + rr) * ldl
                                  + (size_t)(t - 1) * O_DIM + cl * 32;
                float v[32];
                float mx = -3.4e38f;
                #pragma unroll
                for (int j = 0; j < 32; j++) { v[j] = ald_f(rowp + j); mx = fmaxf(mx, v[j]); }
                #pragma unroll
                for (int off = 1; off < 16; off <<= 1) mx = fmaxf(mx, __shfl_xor(mx, off, 16));
                float s = 0.f;
                #pragma unroll
                for (int j = 0; j < 32; j++) { v[j] = __expf(v[j] - mx); s += v[j]; }
                #pragma unroll
                for (int off = 1; off < 16; off <<= 1) s += __shfl_xor(s, off, 16);
                float inv = 1.f / s;
                #pragma unroll
                for (int j = 0; j < 32; j += 2) {
                    unsigned int pk = (unsigned int)f2bf(v[j] * inv)
                                    | ((unsigned int)f2bf(v[j + 1] * inv) << 16);
                    int byte = ((rr * O_DIM + cl * 32 + j) * 2) ^ ((rr & 7) << 4);
                    *(unsigned int*)((char*)xs + byte) = pk;
                }
            } else {
                const short* rowp = a.yb + (size_t)(r0 + rr) * O_DIM + cl * 32;
                #pragma unroll
                for (int j = 0; j < 32; j += 2) {
                    unsigned int pk = (unsigned int)(unsigned short)rowp[j]
                                    | ((unsigned int)(unsigned short)rowp[j + 1] << 16);
                    int byte = ((rr * O_DIM + cl * 32 + j) * 2) ^ ((rr & 7) << 4);
                    *(unsigned int*)((char*)xs + byte) = pk;
                }
            }
            __syncthreads();
            const int KqI = O_DIM >> 2;            // 128
            const int KqH = M >> 2;                // 256
            const short* wrI = a.wih0 + (size_t)(m0 + lrow) * O_DIM + wave * KqI + ko8;
            const short* wzI = wrI + (size_t)M * O_DIM;
            const short* wnI = wrI + (size_t)2 * M * O_DIM;
            const short* wrH = a.whh0 + (size_t)(m0 + lrow) * M + wave * KqH + ko8;
            const short* wzH = wrH + (size_t)M * M;
            const short* wnH = wrH + (size_t)2 * M * M;
            floatx4 ar = {0.f, 0.f, 0.f, 0.f};
            floatx4 az = {0.f, 0.f, 0.f, 0.f};
            floatx4 ai = {0.f, 0.f, 0.f, 0.f};
            floatx4 ah = {0.f, 0.f, 0.f, 0.f};
            #pragma unroll
            for (int k = 0; k < KqI; k += 32) {
                int abyte = ((lrow * O_DIM + wave * KqI + ko8 + k) * 2) ^ ((lrow & 7) << 4);
                bf16x8 av = *(const bf16x8*)((const char*)xs + abyte);
                ar = __builtin_amdgcn_mfma_f32_16x16x32_bf16(av, *(const bf16x8*)(wrI + k), ar, 0, 0, 0);
                az = __builtin_amdgcn_mfma_f32_16x16x32_bf16(av, *(const bf16x8*)(wzI + k), az, 0, 0, 0);
                ai = __builtin_amdgcn_mfma_f32_16x16x32_bf16(av, *(const bf16x8*)(wnI + k), ai, 0, 0, 0);
            }
            const short* apH = a.h0b + (size_t)pin * B * M + (size_t)(r0 + lrow) * M + wave * KqH + ko8;
            #pragma unroll
            for (int k = 0; k < KqH; k += 32) {
                bf16x8 av = ald_b8(apH + k);
                ar = __builtin_amdgcn_mfma_f32_16x16x32_bf16(av, *(const bf16x8*)(wrH + k), ar, 0, 0, 0);
                az = __builtin_amdgcn_mfma_f32_16x16x32_bf16(av, *(const bf16x8*)(wzH + k), az, 0, 0, 0);
                ah = __builtin_amdgcn_mfma_f32_16x16x32_bf16(av, *(const bf16x8*)(wnH + k), ah, 0, 0, 0);
            }
            #pragma unroll
            for (int i = 0; i < 4; i++) {
                lds[0][wave][lane][i] = ar[i];
                lds[1][wave][lane][i] = az[i];
                lds[2][wave][lane][i] = ai[i];
                lds[3][wave][lane][i] = ah[i];
            }
            __syncthreads();
            int row = threadIdx.x >> 4, col = threadIdx.x & 15;
            int sl = (row >> 2) * 16 + col, rg = row & 3;
            float sr = lds[0][0][sl][rg] + lds[0][1][sl][rg] + lds[0][2][sl][rg] + lds[0][3][sl][rg];
            float sz = lds[1][0][sl][rg] + lds[1][1][sl][rg] + lds[1][2][sl][rg] + lds[1][3][sl][rg];
            float si = lds[2][0][sl][rg] + lds[2][1][sl][rg] + lds[2][2][sl][rg] + lds[2][3][sl][rg];
            float sh = lds[3][0][sl][rg] + lds[3][1][sl][rg] + lds[3][2][sl][rg] + lds[3][3][sl][rg];
            int b = r0 + row, m = m0 + col;
            float r = sigm(sr + a.bih0[m] + a.bhh0[m]);
            float z = sigm(sz + a.bih0[M + m] + a.bhh0[M + m]);
            float n = tanhf(si + a.bih0[2 * M + m] + r * (sh + a.bhh0[2 * M + m]));
            size_t hi = (size_t)b * M + m;
            float hv = (1.f - z) * n + z * a.h0f[hi];
            a.h0f[hi] = hv;
            ast_h_pair(a.h0b + (size_t)pout * B * M + (size_t)b * M + (m & ~1), hv);
        }
        gridbar(a.flags, a.eps, a.relay, ++epoch, bid);
        // ============ Phase B: gru1 (x = new h0, Kx = M) ===================
        {
            const int Kq = M >> 2;
            const short* wrI = a.wih1 + (size_t)(m0 + lrow) * M + wave * Kq + ko8;
            const short* wzI = wrI + (size_t)M * M;
            const short* wnI = wrI + (size_t)2 * M * M;
            const short* wrH = a.whh1 + (size_t)(m0 + lrow) * M + wave * Kq + ko8;
            const short* wzH = wrH + (size_t)M * M;
            const short* wnH = wrH + (size_t)2 * M * M;
            floatx4 ar = {0.f, 0.f, 0.f, 0.f};
            floatx4 az = {0.f, 0.f, 0.f, 0.f};
            floatx4 ai = {0.f, 0.f, 0.f, 0.f};
            floatx4 ah = {0.f, 0.f, 0.f, 0.f};
            const short* apI = a.h0b + (size_t)pout * B * M + (size_t)(r0 + lrow) * M + wave * Kq + ko8;
            #pragma unroll
            for (int k = 0; k < Kq; k += 32) {
                bf16x8 av = ald_b8(apI + k);
                ar = __builtin_amdgcn_mfma_f32_16x16x32_bf16(av, *(const bf16x8*)(wrI + k), ar, 0, 0, 0);
                az = __builtin_amdgcn_mfma_f32_16x16x32_bf16(av, *(const bf16x8*)(wzI + k), az, 0, 0, 0);
                ai = __builtin_amdgcn_mfma_f32_16x16x32_bf16(av, *(const bf16x8*)(wnI + k), ai, 0, 0, 0);
            }
            const short* apH = a.h1b + (size_t)pin * B * M + (size_t)(r0 + lrow) * M + wave * Kq + ko8;
            #pragma unroll
            for (int k = 0; k < Kq; k += 32) {
                bf16x8 av = ald_b8(apH + k);
                ar = __builtin_amdgcn_mfma_f32_16x16x32_bf16(av, *(const bf16x8*)(wrH + k), ar, 0, 0, 0);
                az = __builtin_amdgcn_mfma_f32_16x16x32_bf16(av, *(const bf16x8*)(wzH + k), az, 0, 0, 0);
                ah = __builtin_amdgcn_mfma_f32_16x16x32_bf16(av, *(const bf16x8*)(wnH + k), ah, 0, 0, 0);
            }
            #pragma unroll
            for (int i = 0; i < 4; i++) {
                lds[0][wave][lane][i] = ar[i];
                lds[1][wave][lane][i] = az[i];
                lds[2][wave][lane][i] = ai[i];
                lds[3][wave][lane][i] = ah[i];
            }
            __syncthreads();
            int row = threadIdx.x >> 4, col = threadIdx.x & 15;
            int sl = (row >> 2) * 16 + col, rg = row & 3;
            float sr = lds[0][0][sl][rg] + lds[0][1][sl][rg] + lds[0][2][sl][rg] + lds[0][3][sl][rg];
            float sz = lds[1][0][sl][rg] + lds[1][1][sl][rg] + lds[1][2][sl][rg] + lds[1][3][sl][rg];
            float si = lds[2][0][sl][rg] + lds[2][1][sl][rg] + lds[2][2][sl][rg] + lds[2][3][sl][rg];
            float sh = lds[3][0][sl][rg] + lds[3][1][sl][rg] + lds[3][2][sl][rg] + lds[3][3][sl][rg];
            int b = r0 + row, m = m0 + col;
            float r = sigm(sr + a.bih1[m] + a.bhh1[m]);
            float z = sigm(sz + a.bih1[M + m] + a.bhh1[M + m]);
            float n = tanhf(si + a.bih1[2 * M + m] + r * (sh + a.bhh1[2 * M + m]));
            size_t hi = (size_t)b * M + m;
            float hv = (1.f - z) * n + z * a.h1f[hi];
            a.h1f[hi] = hv;
            ast_h_pair(a.h1b + (size_t)pout * B * M + (size_t)b * M + (m & ~1), hv);
        }
        gridbar(a.flags, a.eps, a.relay, ++epoch, bid);
        // ============ Phase C: fc1 (2 col-tiles/block) + LN stats ==========
        {
            float* st = a.stats + (size_t)t * 2 * B;
            const int Kq = M >> 2;
            const short* ap = a.h1b + (size_t)pout * B * M + (size_t)(r0 + lrow) * M + wave * Kq + ko8;
            const short* wp[2];
            floatx4 acc[2];
            #pragma unroll
            for (int j = 0; j < 2; ++j) {
                int c0 = (j * 64 + (bid & 63)) * 16;
                wp[j] = a.wfc1 + (size_t)(c0 + lrow) * M + wave * Kq + ko8;
                acc[j] = (floatx4){0.f, 0.f, 0.f, 0.f};
            }
            #pragma unroll
            for (int k = 0; k < Kq; k += 32) {
                bf16x8 av = ald_b8(ap + k);
                #pragma unroll
                for (int j = 0; j < 2; ++j)
                    acc[j] = __builtin_amdgcn_mfma_f32_16x16x32_bf16(av, *(const bf16x8*)(wp[j] + k), acc[j], 0, 0, 0);
            }
            #pragma unroll
            for (int j = 0; j < 2; ++j)
                #pragma unroll
                for (int i = 0; i < 4; i++) lds[j][wave][lane][i] = acc[j][i];
            __syncthreads();
            int row = threadIdx.x >> 4, col = threadIdx.x & 15;
            int sl = (row >> 2) * 16 + col, rg = row & 3;
            #pragma unroll
            for (int j = 0; j < 2; ++j) {
                int c0 = (j * 64 + (bid & 63)) * 16;
                float s = lds[j][0][sl][rg] + lds[j][1][sl][rg]
                        + lds[j][2][sl][rg] + lds[j][3][sl][rg];
                float val = s + a.fc1b[c0 + col];
                ast_f(&a.zb[(size_t)(r0 + row) * LM + c0 + col], val);
                float sv = val, sq = val * val;
                #pragma unroll
                for (int off = 1; off < 16; off <<= 1) {
                    sv += __shfl_xor(sv, off, 16);
                    sq += __shfl_xor(sq, off, 16);
                }
                if ((threadIdx.x & 15) == 0) {
                    atomicAdd(&st[r0 + row], sv);
                    atomicAdd(&st[B + r0 + row], sq);
                }
            }
        }
        gridbar(a.flags, a.eps, a.relay, ++epoch, bid);
        // ============ Phase D: LN + GELU apply (2 elems/thread) ============
        {
            const float* st = a.stats + (size_t)t * 2 * B;
            int e0 = (bid * 256 + threadIdx.x) * 2;      // B*LM = 131072
            int rowd = e0 >> 11;
            float mu = ald_f(&st[rowd]) * (1.f / LM);
            float var = ald_f(&st[B + rowd]) * (1.f / LM) - mu * mu;
            float inv = rsqrtf(var + 1e-5f);
            float ge[2];
            #pragma unroll
            for (int j = 0; j < 2; j++) {
                int e = e0 + j;
                int cc = e & (LM - 1);
                float zn = (ald_f(&a.zb[e]) - mu) * inv * a.lng[cc] + a.lnb[cc];
                ge[j] = 0.5f * zn * (1.f + erff(zn * 0.70710678118654752f));
            }
            unsigned pk = (unsigned)f2bf(ge[0]) | ((unsigned)f2bf(ge[1]) << 16);
            ast_u((unsigned*)(a.zbb + e0), pk);
        }
        gridbar(a.flags, a.eps, a.relay, ++epoch, bid);
        // ============ Phase E: fc2 -> logits out[:, t, :] ==================
        if (bid < 128) {
            int c0 = (bid & 31) * 16;                    // XCD-aware
            int r0e = (bid >> 5) * 16;
            const int Kq = LM >> 2;                      // 512
            const short* ap = a.zbb + (size_t)(r0e + lrow) * LM + wave * Kq + ko8;
            const short* wpp = a.wfc2 + (size_t)(c0 + lrow) * LM + wave * Kq + ko8;
            floatx4 acc = {0.f, 0.f, 0.f, 0.f};
            #pragma unroll 4
            for (int k = 0; k < Kq; k += 32) {
                bf16x8 av = ald_b8(ap + k);
                bf16x8 bv = *(const bf16x8*)(wpp + k);
                acc = __builtin_amdgcn_mfma_f32_16x16x32_bf16(av, bv, acc, 0, 0, 0);
            }
            #pragma unroll
            for (int i = 0; i < 4; i++) lds[0][wave][lane][i] = acc[i];
            __syncthreads();
            int row = threadIdx.x >> 4, col = threadIdx.x & 15;
            int sl = (row >> 2) * 16 + col, rg = row & 3;
            float s = lds[0][0][sl][rg] + lds[0][1][sl][rg]
                    + lds[0][2][sl][rg] + lds[0][3][sl][rg];
            ast_f(&a.out[(size_t)(r0e + row) * ldl + (size_t)t * O_DIM + c0 + col],
                  s + a.fc2b[c0 + col]);
        }
        gridbar(a.flags, a.eps, a.relay, ++epoch, bid);
    }
}

// ===========================================================================
extern "C" void kernel_launch(void* const* d_in, const int* in_sizes, int n_in,
                              void* d_out, int out_size, void* d_ws, size_t ws_size,
                              hipStream_t stream) {
    const float* X        = (const float*)d_in[0];
    const float* Y0       = (const float*)d_in[1];
    const float* enc_Wih0 = (const float*)d_in[2];
    const float* enc_Whh0 = (const float*)d_in[3];
    const float* enc_bih0 = (const float*)d_in[4];
    const float* enc_bhh0 = (const float*)d_in[5];
    const float* enc_Wih1 = (const float*)d_in[6];
    const float* enc_Whh1 = (const float*)d_in[7];
    const float* enc_bih1 = (const float*)d_in[8];
    const float* enc_bhh1 = (const float*)d_in[9];
    const float* dec_Wih0 = (const float*)d_in[10];
    const float* dec_Whh0 = (const float*)d_in[11];
    const float* dec_bih0 = (const float*)d_in[12];
    const float* dec_bhh0 = (const float*)d_in[13];
    const float* dec_Wih1 = (const float*)d_in[14];
    const float* dec_Whh1 = (const float*)d_in[15];
    const float* dec_bih1 = (const float*)d_in[16];
    const float* dec_bhh1 = (const float*)d_in[17];
    const float* fc1_w    = (const float*)d_in[18];
    const float* fc1_b    = (const float*)d_in[19];
    const float* ln_g     = (const float*)d_in[20];
    const float* ln_b     = (const float*)d_in[21];
    const float* fc2_w    = (const float*)d_in[22];
    const float* fc2_b    = (const float*)d_in[23];
    float* out = (float*)d_out;

    // ---- workspace carve-up ----
    char* p = (char*)d_ws;
    auto carve = [&](size_t bytes) {
        void* r = p;
        p += (bytes + 255) & ~(size_t)255;
        return r;
    };
    short* Xt    = (short*)carve((size_t)TIN * B * N_IN * 2);
    short* seqA  = (short*)carve((size_t)TIN * B * M * 2);
    float* gi_ch = (float*)carve((size_t)CH * B * M3 * 4);
    short* we_ih0 = (short*)carve((size_t)M3 * N_IN * 2);
    short* we_hh0 = (short*)carve((size_t)M3 * M * 2);
    short* we_ih1 = (short*)carve((size_t)M3 * M * 2);
    short* we_hh1 = (short*)carve((size_t)M3 * M * 2);
    short* wd_ih0 = (short*)carve((size_t)M3 * O_DIM * 2);
    short* wd_hh0 = (short*)carve((size_t)M3 * M * 2);
    short* wd_ih1 = (short*)carve((size_t)M3 * M * 2);
    short* wd_hh1 = (short*)carve((size_t)M3 * M * 2);
    short* wfc1   = (short*)carve((size_t)LM * M * 2);
    short* wfc2   = (short*)carve((size_t)O_DIM * LM * 2);
    float* h0f = (float*)carve((size_t)B * M * 4);
    float* h1f = (float*)carve((size_t)B * M * 4);
    short* h0b = (short*)carve((size_t)2 * B * M * 2);   // ping-pong
    short* h1b = (short*)carve((size_t)2 * B * M * 2);
    short* yb  = (short*)carve((size_t)B * O_DIM * 2);
    float* zb  = (float*)carve((size_t)B * LM * 4);
    short* zbb = (short*)carve((size_t)B * LM * 2);
    float* lnstats = (float*)carve((size_t)TDEC * 2 * B * 4);
    unsigned* eflags = (unsigned*)carve((size_t)NB * 32 * 4);  // padded flags
    unsigned* eeps   = (unsigned*)carve(256);
    unsigned* erelay = (unsigned*)carve(2048);
    unsigned* dflags = (unsigned*)carve((size_t)NB * 32 * 4);
    unsigned* deps   = (unsigned*)carve(256);
    unsigned* drelay = (unsigned*)carve(2048);

    auto cast = [&](const float* src, short* dst, int n) {
        cast_bf<<<(n + 255) / 256, 256, 0, stream>>>(src, dst, n);
    };
    cast(enc_Wih0, we_ih0, M3 * N_IN);
    cast(enc_Whh0, we_hh0, M3 * M);
    cast(enc_Wih1, we_ih1, M3 * M);
    cast(enc_Whh1, we_hh1, M3 * M);
    cast(dec_Wih0, wd_ih0, M3 * O_DIM);
    cast(dec_Whh0, wd_hh0, M3 * M);
    cast(dec_Wih1, wd_ih1, M3 * M);
    cast(dec_Whh1, wd_hh1, M3 * M);
    cast(fc1_w, wfc1, LM * M);
    cast(fc2_w, wfc2, O_DIM * LM);
    cast(Y0, yb, B * O_DIM);
    transpose_X_bf<<<(TIN * B * N_IN) / 256, 256, 0, stream>>>(X, Xt);

    hipMemsetAsync(h0f, 0, (size_t)B * M * 4, stream);
    hipMemsetAsync(h1f, 0, (size_t)B * M * 4, stream);
    hipMemsetAsync(h0b, 0, (size_t)B * M * 2, stream);   // parity-0 buffer
    hipMemsetAsync(h1b, 0, (size_t)B * M * 2, stream);
    hipMemsetAsync(lnstats, 0, (size_t)TDEC * 2 * B * 4, stream);
    hipMemsetAsync(eflags, 0, (size_t)NB * 32 * 4, stream);
    hipMemsetAsync(eeps, 0, 256, stream);
    hipMemsetAsync(erelay, 0, 2048, stream);
    hipMemsetAsync(dflags, 0, (size_t)NB * 32 * 4, stream);
    hipMemsetAsync(deps, 0, 256, stream);
    hipMemsetAsync(drelay, 0, 2048, stream);

    // -------------------- encoder (one mega-kernel) -----------------------
    EncArgs ea;
    ea.Xt = Xt; ea.seqA = seqA; ea.gi = gi_ch;
    ea.wih0 = we_ih0; ea.whh0 = we_hh0; ea.bih0 = enc_bih0; ea.bhh0 = enc_bhh0;
    ea.wih1 = we_ih1; ea.whh1 = we_hh1; ea.bih1 = enc_bih1; ea.bhh1 = enc_bhh1;
    ea.h0f = h0f; ea.h1f = h1f; ea.h0b = h0b; ea.h1b = h1b;
    ea.flags = eflags; ea.eps = eeps; ea.relay = erelay;
    enc_mega<<<dim3(NB), dim3(256), 0, stream>>>(ea);

    // -------------------- decoder (one mega-kernel) -----------------------
    DecArgs da;
    da.yb = yb;
    da.wih0 = wd_ih0; da.whh0 = wd_hh0; da.bih0 = dec_bih0; da.bhh0 = dec_bhh0;
    da.wih1 = wd_ih1; da.whh1 = wd_hh1; da.bih1 = dec_bih1; da.bhh1 = dec_bhh1;
    da.wfc1 = wfc1; da.fc1b = fc1_b;
    da.lng = ln_g; da.lnb = ln_b;
    da.wfc2 = wfc2; da.fc2b = fc2_b;
    da.h0f = h0f; da.h1f = h1f; da.h0b = h0b; da.h1b = h1b;
    da.zb = zb; da.zbb = zbb; da.stats = lnstats; da.out = out;
    da.flags = dflags; da.eps = deps; da.relay = drelay;
    dec_mega<<<dim3(NB), dim3(256), 0, stream>>>(da);
}

// Round 7
// 6379.775 us; speedup vs baseline: 2.2805x; 1.1936x over previous
//
#include <hip/hip_runtime.h>
#include <math.h>

#define B 64
#define TIN 128
#define N_IN 256
#define M 1024
#define O_DIM 512
#define LM 2048
#define TDEC 64
#define M3 3072
#define CH 8     // encoder gi timestep chunk
#define NB 256   // grid blocks for the two mega-kernels (1 block/CU)

typedef short bf16x8 __attribute__((ext_vector_type(8)));
typedef float floatx4 __attribute__((ext_vector_type(4)));
typedef unsigned long long u64_t;

__device__ __forceinline__ unsigned short f2bf(float f) {
    unsigned int u = __float_as_uint(f);
    u += 0x7FFFu + ((u >> 16) & 1u);      // round-to-nearest-even
    return (unsigned short)(u >> 16);
}
__device__ __forceinline__ float sigm(float x) { return 1.f / (1.f + expf(-x)); }

// ---- relaxed agent-scope accessors: per-access MALL coherence, NO fences ----
__device__ __forceinline__ float ald_f(const float* p) {
    return __hip_atomic_load((float*)p, __ATOMIC_RELAXED, __HIP_MEMORY_SCOPE_AGENT);
}
__device__ __forceinline__ void ast_f(float* p, float v) {
    __hip_atomic_store(p, v, __ATOMIC_RELAXED, __HIP_MEMORY_SCOPE_AGENT);
}
__device__ __forceinline__ void ast_u(unsigned* p, unsigned v) {
    __hip_atomic_store(p, v, __ATOMIC_RELAXED, __HIP_MEMORY_SCOPE_AGENT);
}
__device__ __forceinline__ bf16x8 ald_b8(const short* p) {
    u64_t lo = __hip_atomic_load((u64_t*)p, __ATOMIC_RELAXED, __HIP_MEMORY_SCOPE_AGENT);
    u64_t hi = __hip_atomic_load((u64_t*)(p + 4), __ATOMIC_RELAXED, __HIP_MEMORY_SCOPE_AGENT);
    union { u64_t q[2]; bf16x8 v; } u;
    u.q[0] = lo; u.q[1] = hi;
    return u.v;
}
// pack (even,odd) col pair to one u32 atomic store; all threads call, even store
__device__ __forceinline__ void ast_h_pair(short* addr_even, float hv) {
    unsigned short hb16 = f2bf(hv);
    int partner = __shfl_xor((int)hb16, 1, 64);
    if ((threadIdx.x & 1) == 0) {
        unsigned pair = (unsigned)hb16 | ((unsigned)(unsigned short)partner << 16);
        __hip_atomic_store((unsigned*)addr_even, pair,
                           __ATOMIC_RELAXED, __HIP_MEMORY_SCOPE_AGENT);
    }
}

// ---------------------------------------------------------------------------
// Symmetric all-poll grid barrier, fence-free. Each block release... no:
// relaxed-stores its padded flag; ALL blocks poll ALL 256 flags (one per
// thread). ~1.5 MALL hops. __syncthreads() on entry drains vmcnt so prior
// agent-atomic writes are globally visible before the flag store. No
// buffer_inv/wbl2 -> L2 stays warm. Bounded spin as hang escape hatch.
// ---------------------------------------------------------------------------
__device__ __forceinline__ void gridbar(unsigned* flags, unsigned epoch, int bid) {
    __syncthreads();
    if (threadIdx.x == 0)
        __hip_atomic_store(&flags[(size_t)bid * 32], epoch, __ATOMIC_RELAXED,
                           __HIP_MEMORY_SCOPE_AGENT);
    unsigned g = 0;
    while (__hip_atomic_load(&flags[(size_t)threadIdx.x * 32],
                             __ATOMIC_RELAXED, __HIP_MEMORY_SCOPE_AGENT) < epoch) {
        __builtin_amdgcn_s_sleep(2);
        if (++g > (1u << 22)) break;   // escape: fail loud, don't hang
    }
    __syncthreads();
}

// ---------------------------------------------------------------------------
// fp32 -> bf16 cast (weights, Y0)
// ---------------------------------------------------------------------------
__global__ __launch_bounds__(256) void cast_bf(const float* __restrict__ in,
                                               short* __restrict__ out, int n) {
    int i = blockIdx.x * 256 + threadIdx.x;
    if (i < n) out[i] = (short)f2bf(in[i]);
}

// ---------------------------------------------------------------------------
// X (B,TIN,N) fp32 -> Xt (TIN,B,N) bf16
// ---------------------------------------------------------------------------
__global__ __launch_bounds__(256) void transpose_X_bf(const float* __restrict__ X,
                                                      short* __restrict__ Xt) {
    int idx = blockIdx.x * 256 + threadIdx.x;   // t*(B*N) + b*N + n
    int n = idx & (N_IN - 1);
    int b = (idx >> 8) & (B - 1);
    int t = idx >> 14;
    Xt[idx] = (short)f2bf(X[(b * TIN + t) * N_IN + n]);
}

// ===========================================================================
// ENCODER mega-kernel. Weights via normal cached loads (L2-resident),
// cross-block state via batched agent atomics. seqA normal with ONE fenced
// barrier at the layer0->layer1 transition.
// ===========================================================================
struct EncArgs {
    const short* Xt;       // (TIN,B,N) bf16
    short* seqA;           // (TIN,B,M) bf16   layer-0 outputs (normal access)
    float* gi;             // (CH,B,M3) fp32   chunk scratch (atomic access)
    const short* wih0; const short* whh0; const float* bih0; const float* bhh0;
    const short* wih1; const short* whh1; const float* bih1; const float* bhh1;
    float* h0f; float* h1f;
    short* h0b; short* h1b;      // ping-pong (2,B,M), atomic access
    unsigned* flags;
};

__global__ __launch_bounds__(256, 1) void enc_mega(EncArgs a) {
    __shared__ float lds[3][4][64][4];          // 12 KB
    const int bid  = blockIdx.x;
    const int wave = threadIdx.x >> 6;
    const int lane = threadIdx.x & 63;
    const int lrow = lane & 15;
    const int ko8  = (lane >> 4) * 8;
    unsigned epoch = 0;

    for (int layer = 0; layer < 2; ++layer) {
        const short* Wih = layer ? a.wih1 : a.wih0;
        const short* Whh = layer ? a.whh1 : a.whh0;
        const float* bih = layer ? a.bih1 : a.bih0;
        const float* bhh = layer ? a.bhh1 : a.bhh0;
        const short* inseq = layer ? a.seqA : a.Xt;
        const int K = layer ? M : N_IN;
        float* hf = layer ? a.h1f : a.h0f;
        short* hb = layer ? a.h1b : a.h0b;

        for (int c = 0; c < TIN / CH; ++c) {
            // ---- GI phase: gi[tt,b,:] = inseq[chunk] @ Wih^T + bih ----
            // XCD-grouped: each XCD owns 24 col-tiles (weight panel in one L2)
            {
                const short* A = inseq + (size_t)c * CH * B * K;
                int xcd = bid & 7;
                int l   = bid >> 3;                    // 0..31
                int w4  = l * 4 + wave;                // 0..127
                for (int i = 0; i < 6; ++i) {
                    int gt   = w4 * 6 + i;             // 0..767
                    int colt = xcd * 24 + (gt % 24);   // 0..191
                    int rowt = gt / 24;                // 0..31
                    int r0 = rowt * 16;
                    int c0 = colt * 16;
                    const short* ap = A + (size_t)(r0 + lrow) * K + ko8;
                    const short* wp = Wih + (size_t)(c0 + lrow) * K + ko8;
                    floatx4 acc = {0.f, 0.f, 0.f, 0.f};
                    #pragma unroll 4
                    for (int k = 0; k < K; k += 32) {
                        bf16x8 av = *(const bf16x8*)(ap + k);   // normal (Xt/seqA)
                        bf16x8 bv = *(const bf16x8*)(wp + k);
                        acc = __builtin_amdgcn_mfma_f32_16x16x32_bf16(av, bv, acc, 0, 0, 0);
                    }
                    int col = c0 + lrow;
                    float bv = bih[col];
                    int rb = r0 + (lane >> 4) * 4;
                    #pragma unroll
                    for (int q = 0; q < 4; q++)
                        ast_f(&a.gi[(size_t)(rb + q) * M3 + col], acc[q] + bv);
                }
            }
            gridbar(a.flags, ++epoch, bid);
            // ---- 8 GRU steps; block owns (m-tile = bid&63, r-tile = bid>>6)
            for (int tt = 0; tt < CH; ++tt) {
                int t = c * CH + tt;
                int pin = t & 1, pout = pin ^ 1;
                const short* h_in = hb + (size_t)pin * B * M;
                float* gi_t = a.gi + (size_t)tt * B * M3;
                int m0 = (bid & 63) * 16;
                int r0 = (bid >> 6) * 16;
                const int Kq = M >> 2;                 // 256
                const short* ap = h_in + (size_t)(r0 + lrow) * M + wave * Kq + ko8;
                // ---- batched atomic operand fetch (one MALL latency) ------
                bf16x8 hreg[8];
                #pragma unroll
                for (int k = 0; k < 8; ++k) hreg[k] = ald_b8(ap + k * 32);
                const short* wr = Whh + (size_t)(m0 + lrow) * M + wave * Kq + ko8;
                const short* wz = wr + (size_t)M * M;
                const short* wn = wr + (size_t)2 * M * M;
                floatx4 ar = {0.f, 0.f, 0.f, 0.f};
                floatx4 az = {0.f, 0.f, 0.f, 0.f};
                floatx4 ah = {0.f, 0.f, 0.f, 0.f};
                #pragma unroll
                for (int k = 0; k < 8; ++k) {
                    ar = __builtin_amdgcn_mfma_f32_16x16x32_bf16(hreg[k], *(const bf16x8*)(wr + k * 32), ar, 0, 0, 0);
                    az = __builtin_amdgcn_mfma_f32_16x16x32_bf16(hreg[k], *(const bf16x8*)(wz + k * 32), az, 0, 0, 0);
                    ah = __builtin_amdgcn_mfma_f32_16x16x32_bf16(hreg[k], *(const bf16x8*)(wn + k * 32), ah, 0, 0, 0);
                }
                #pragma unroll
                for (int i = 0; i < 4; i++) {
                    lds[0][wave][lane][i] = ar[i];
                    lds[1][wave][lane][i] = az[i];
                    lds[2][wave][lane][i] = ah[i];
                }
                __syncthreads();
                int row = threadIdx.x >> 4, col = threadIdx.x & 15;
                int sl = (row >> 2) * 16 + col, rg = row & 3;
                float sr = lds[0][0][sl][rg] + lds[0][1][sl][rg] + lds[0][2][sl][rg] + lds[0][3][sl][rg];
                float sz = lds[1][0][sl][rg] + lds[1][1][sl][rg] + lds[1][2][sl][rg] + lds[1][3][sl][rg];
                float sn = lds[2][0][sl][rg] + lds[2][1][sl][rg] + lds[2][2][sl][rg] + lds[2][3][sl][rg];
                int b = r0 + row, m = m0 + col;
                float gr = ald_f(&gi_t[(size_t)b * M3 + m]);
                float gz = ald_f(&gi_t[(size_t)b * M3 + M + m]);
                float gn = ald_f(&gi_t[(size_t)b * M3 + 2 * M + m]);
                float r = sigm(gr + sr + bhh[m]);
                float z = sigm(gz + sz + bhh[M + m]);
                float n = tanhf(gn + r * (sn + bhh[2 * M + m]));
                size_t hi = (size_t)b * M + m;
                float hv = (1.f - z) * n + z * hf[hi];   // hf block-private
                hf[hi] = hv;
                if (layer == 0) a.seqA[(size_t)t * B * M + hi] = (short)f2bf(hv);
                ast_h_pair(hb + (size_t)pout * B * M + (size_t)b * M + (m & ~1),
                           hv);
                gridbar(a.flags, ++epoch, bid);
            }
        }
        if (layer == 0) {
            // one fenced barrier: flush dirty seqA lines from every L2 and
            // invalidate, so layer-1 GI can read seqA with normal cached loads
            __builtin_amdgcn_fence(__ATOMIC_RELEASE, "agent");
            gridbar(a.flags, ++epoch, bid);
            __builtin_amdgcn_fence(__ATOMIC_ACQUIRE, "agent");
        }
    }
}

// ===========================================================================
// DECODER mega-kernel: 5 fence-free-barrier-separated phases per step.
// Batched atomic operand loads; deterministic LN stats via per-block partials.
// ===========================================================================
struct DecArgs {
    const short* yb;                         // (B,O) bf16 initial y (normal)
    const short* wih0; const short* whh0; const float* bih0; const float* bhh0;
    const short* wih1; const short* whh1; const float* bih1; const float* bhh1;
    const short* wfc1; const float* fc1b;
    const float* lng; const float* lnb;
    const short* wfc2; const float* fc2b;
    float* h0f; float* h1f;                  // block-private fp32 state
    short* h0b; short* h1b;                  // ping-pong (2,B,M), atomic
    float* zb;                               // (B,LM) fp32, atomic
    short* zbb;                              // (B,LM) bf16, atomic
    float* part;                             // (TDEC,2,64,64) fp32 partials
    float* out;                              // (B,TDEC,O) fp32 logits, atomic
    unsigned* flags;
};

__global__ __launch_bounds__(256, 1) void dec_mega(DecArgs a) {
    __shared__ short xs[16 * O_DIM];         // 16 KB, XOR-swizzled A rows
    __shared__ float lds[4][4][64][4];       // 16 KB
    __shared__ float redD[2];
    const int bid  = blockIdx.x;
    const int wave = threadIdx.x >> 6;
    const int lane = threadIdx.x & 63;
    const int lrow = lane & 15;
    const int ko8  = (lane >> 4) * 8;
    const int ldl  = TDEC * O_DIM;
    unsigned epoch = 0;

    for (int t = 0; t < TDEC; ++t) {
        int pin = t & 1, pout = pin ^ 1;
        int m0 = (bid & 63) * 16;            // XCD-aware: bid%8 constant per m0
        int r0 = (bid >> 6) * 16;
        // ============ Phase A: gru0 + fused softmax(prev logits) ===========
        {
            // issue hidden-operand batch FIRST (hides MALL latency under
            // softmax + input-side MFMAs)
            const int KqH = M >> 2;                // 256
            const short* apH = a.h0b + (size_t)pin * B * M + (size_t)(r0 + lrow) * M + wave * KqH + ko8;
            bf16x8 hreg[8];
            #pragma unroll
            for (int k = 0; k < 8; ++k) hreg[k] = ald_b8(apH + k * 32);

            int rr = wave * 4 + (lane >> 4);       // row 0..15 of this block
            int cl = lane & 15;
            if (t > 0) {
                const float* rowp = a.out + (size_t)(r0 + rr) * ldl
                                  + (size_t)(t - 1) * O_DIM + cl * 32;
                float v[32];
                float mx = -3.4e38f;
                #pragma unroll
                for (int j = 0; j < 32; j++) { v[j] = ald_f(rowp + j); mx = fmaxf(mx, v[j]); }
                #pragma unroll
                for (int off = 1; off < 16; off <<= 1) mx = fmaxf(mx, __shfl_xor(mx, off, 16));
                float s = 0.f;
                #pragma unroll
                for (int j = 0; j < 32; j++) { v[j] = __expf(v[j] - mx); s += v[j]; }
                #pragma unroll
                for (int off = 1; off < 16; off <<= 1) s += __shfl_xor(s, off, 16);
                float inv = 1.f / s;
                #pragma unroll
                for (int j = 0; j < 32; j += 2) {
                    unsigned int pk = (unsigned int)f2bf(v[j] * inv)
                                    | ((unsigned int)f2bf(v[j + 1] * inv) << 16);
                    int byte = ((rr * O_DIM + cl * 32 + j) * 2) ^ ((rr & 7) << 4);
                    *(unsigned int*)((char*)xs + byte) = pk;
                }
            } else {
                const short* rowp = a.yb + (size_t)(r0 + rr) * O_DIM + cl * 32;
                #pragma unroll
                for (int j = 0; j < 32; j += 2) {
                    unsigned int pk = (unsigned int)(unsigned short)rowp[j]
                                    | ((unsigned int)(unsigned short)rowp[j + 1] << 16);
                    int byte = ((rr * O_DIM + cl * 32 + j) * 2) ^ ((rr & 7) << 4);
                    *(unsigned int*)((char*)xs + byte) = pk;
                }
            }
            __syncthreads();
            const int KqI = O_DIM >> 2;            // 128
            const short* wrI = a.wih0 + (size_t)(m0 + lrow) * O_DIM + wave * KqI + ko8;
            const short* wzI = wrI + (size_t)M * O_DIM;
            const short* wnI = wrI + (size_t)2 * M * O_DIM;
            const short* wrH = a.whh0 + (size_t)(m0 + lrow) * M + wave * KqH + ko8;
            const short* wzH = wrH + (size_t)M * M;
            const short* wnH = wrH + (size_t)2 * M * M;
            floatx4 ar = {0.f, 0.f, 0.f, 0.f};
            floatx4 az = {0.f, 0.f, 0.f, 0.f};
            floatx4 ai = {0.f, 0.f, 0.f, 0.f};
            floatx4 ah = {0.f, 0.f, 0.f, 0.f};
            #pragma unroll
            for (int k = 0; k < KqI; k += 32) {
                int abyte = ((lrow * O_DIM + wave * KqI + ko8 + k) * 2) ^ ((lrow & 7) << 4);
                bf16x8 av = *(const bf16x8*)((const char*)xs + abyte);
                ar = __builtin_amdgcn_mfma_f32_16x16x32_bf16(av, *(const bf16x8*)(wrI + k), ar, 0, 0, 0);
                az = __builtin_amdgcn_mfma_f32_16x16x32_bf16(av, *(const bf16x8*)(wzI + k), az, 0, 0, 0);
                ai = __builtin_amdgcn_mfma_f32_16x16x32_bf16(av, *(const bf16x8*)(wnI + k), ai, 0, 0, 0);
            }
            #pragma unroll
            for (int k = 0; k < 8; ++k) {
                ar = __builtin_amdgcn_mfma_f32_16x16x32_bf16(hreg[k], *(const bf16x8*)(wrH + k * 32), ar, 0, 0, 0);
                az = __builtin_amdgcn_mfma_f32_16x16x32_bf16(hreg[k], *(const bf16x8*)(wzH + k * 32), az, 0, 0, 0);
                ah = __builtin_amdgcn_mfma_f32_16x16x32_bf16(hreg[k], *(const bf16x8*)(wnH + k * 32), ah, 0, 0, 0);
            }
            #pragma unroll
            for (int i = 0; i < 4; i++) {
                lds[0][wave][lane][i] = ar[i];
                lds[1][wave][lane][i] = az[i];
                lds[2][wave][lane][i] = ai[i];
                lds[3][wave][lane][i] = ah[i];
            }
            __syncthreads();
            int row = threadIdx.x >> 4, col = threadIdx.x & 15;
            int sl = (row >> 2) * 16 + col, rg = row & 3;
            float sr = lds[0][0][sl][rg] + lds[0][1][sl][rg] + lds[0][2][sl][rg] + lds[0][3][sl][rg];
            float sz = lds[1][0][sl][rg] + lds[1][1][sl][rg] + lds[1][2][sl][rg] + lds[1][3][sl][rg];
            float si = lds[2][0][sl][rg] + lds[2][1][sl][rg] + lds[2][2][sl][rg] + lds[2][3][sl][rg];
            float sh = lds[3][0][sl][rg] + lds[3][1][sl][rg] + lds[3][2][sl][rg] + lds[3][3][sl][rg];
            int b = r0 + row, m = m0 + col;
            float r = sigm(sr + a.bih0[m] + a.bhh0[m]);
            float z = sigm(sz + a.bih0[M + m] + a.bhh0[M + m]);
            float n = tanhf(si + a.bih0[2 * M + m] + r * (sh + a.bhh0[2 * M + m]));
            size_t hi = (size_t)b * M + m;
            float hv = (1.f - z) * n + z * a.h0f[hi];
            a.h0f[hi] = hv;
            ast_h_pair(a.h0b + (size_t)pout * B * M + (size_t)b * M + (m & ~1), hv);
        }
        gridbar(a.flags, ++epoch, bid);
        // ============ Phase B: gru1 (x = new h0, Kx = M) ===================
        {
            const int Kq = M >> 2;
            const short* apI = a.h0b + (size_t)pout * B * M + (size_t)(r0 + lrow) * M + wave * Kq + ko8;
            const short* apH = a.h1b + (size_t)pin * B * M + (size_t)(r0 + lrow) * M + wave * Kq + ko8;
            bf16x8 ireg[8], hreg[8];
            #pragma unroll
            for (int k = 0; k < 8; ++k) ireg[k] = ald_b8(apI + k * 32);
            #pragma unroll
            for (int k = 0; k < 8; ++k) hreg[k] = ald_b8(apH + k * 32);
            const short* wrI = a.wih1 + (size_t)(m0 + lrow) * M + wave * Kq + ko8;
            const short* wzI = wrI + (size_t)M * M;
            const short* wnI = wrI + (size_t)2 * M * M;
            const short* wrH = a.whh1 + (size_t)(m0 + lrow) * M + wave * Kq + ko8;
            const short* wzH = wrH + (size_t)M * M;
            const short* wnH = wrH + (size_t)2 * M * M;
            floatx4 ar = {0.f, 0.f, 0.f, 0.f};
            floatx4 az = {0.f, 0.f, 0.f, 0.f};
            floatx4 ai = {0.f, 0.f, 0.f, 0.f};
            floatx4 ah = {0.f, 0.f, 0.f, 0.f};
            #pragma unroll
            for (int k = 0; k < 8; ++k) {
                ar = __builtin_amdgcn_mfma_f32_16x16x32_bf16(ireg[k], *(const bf16x8*)(wrI + k * 32), ar, 0, 0, 0);
                az = __builtin_amdgcn_mfma_f32_16x16x32_bf16(ireg[k], *(const bf16x8*)(wzI + k * 32), az, 0, 0, 0);
                ai = __builtin_amdgcn_mfma_f32_16x16x32_bf16(ireg[k], *(const bf16x8*)(wnI + k * 32), ai, 0, 0, 0);
            }
            #pragma unroll
            for (int k = 0; k < 8; ++k) {
                ar = __builtin_amdgcn_mfma_f32_16x16x32_bf16(hreg[k], *(const bf16x8*)(wrH + k * 32), ar, 0, 0, 0);
                az = __builtin_amdgcn_mfma_f32_16x16x32_bf16(hreg[k], *(const bf16x8*)(wzH + k * 32), az, 0, 0, 0);
                ah = __builtin_amdgcn_mfma_f32_16x16x32_bf16(hreg[k], *(const bf16x8*)(wnH + k * 32), ah, 0, 0, 0);
            }
            #pragma unroll
            for (int i = 0; i < 4; i++) {
                lds[0][wave][lane][i] = ar[i];
                lds[1][wave][lane][i] = az[i];
                lds[2][wave][lane][i] = ai[i];
                lds[3][wave][lane][i] = ah[i];
            }
            __syncthreads();
            int row = threadIdx.x >> 4, col = threadIdx.x & 15;
            int sl = (row >> 2) * 16 + col, rg = row & 3;
            float sr = lds[0][0][sl][rg] + lds[0][1][sl][rg] + lds[0][2][sl][rg] + lds[0][3][sl][rg];
            float sz = lds[1][0][sl][rg] + lds[1][1][sl][rg] + lds[1][2][sl][rg] + lds[1][3][sl][rg];
            float si = lds[2][0][sl][rg] + lds[2][1][sl][rg] + lds[2][2][sl][rg] + lds[2][3][sl][rg];
            float sh = lds[3][0][sl][rg] + lds[3][1][sl][rg] + lds[3][2][sl][rg] + lds[3][3][sl][rg];
            int b = r0 + row, m = m0 + col;
            float r = sigm(sr + a.bih1[m] + a.bhh1[m]);
            float z = sigm(sz + a.bih1[M + m] + a.bhh1[M + m]);
            float n = tanhf(si + a.bih1[2 * M + m] + r * (sh + a.bhh1[2 * M + m]));
            size_t hi = (size_t)b * M + m;
            float hv = (1.f - z) * n + z * a.h1f[hi];
            a.h1f[hi] = hv;
            ast_h_pair(a.h1b + (size_t)pout * B * M + (size_t)b * M + (m & ~1), hv);
        }
        gridbar(a.flags, ++epoch, bid);
        // ====== Phase C: fc1 (2 col-tiles/block) + deterministic partials ==
        {
            const int Kq = M >> 2;
            const short* ap = a.h1b + (size_t)pout * B * M + (size_t)(r0 + lrow) * M + wave * Kq + ko8;
            bf16x8 hreg[8];
            #pragma unroll
            for (int k = 0; k < 8; ++k) hreg[k] = ald_b8(ap + k * 32);
            const short* wp0 = a.wfc1 + (size_t)((0 * 64 + (bid & 63)) * 16 + lrow) * M + wave * Kq + ko8;
            const short* wp1 = a.wfc1 + (size_t)((1 * 64 + (bid & 63)) * 16 + lrow) * M + wave * Kq + ko8;
            floatx4 acc0 = {0.f, 0.f, 0.f, 0.f};
            floatx4 acc1 = {0.f, 0.f, 0.f, 0.f};
            #pragma unroll
            for (int k = 0; k < 8; ++k) {
                acc0 = __builtin_amdgcn_mfma_f32_16x16x32_bf16(hreg[k], *(const bf16x8*)(wp0 + k * 32), acc0, 0, 0, 0);
                acc1 = __builtin_amdgcn_mfma_f32_16x16x32_bf16(hreg[k], *(const bf16x8*)(wp1 + k * 32), acc1, 0, 0, 0);
            }
            #pragma unroll
            for (int i = 0; i < 4; i++) {
                lds[0][wave][lane][i] = acc0[i];
                lds[1][wave][lane][i] = acc1[i];
            }
            __syncthreads();
            int row = threadIdx.x >> 4, col = threadIdx.x & 15;
            int sl = (row >> 2) * 16 + col, rg = row & 3;
            float svt = 0.f, sqt = 0.f;
            #pragma unroll
            for (int j = 0; j < 2; ++j) {
                int c0 = (j * 64 + (bid & 63)) * 16;
                float s = lds[j][0][sl][rg] + lds[j][1][sl][rg]
                        + lds[j][2][sl][rg] + lds[j][3][sl][rg];
                float val = s + a.fc1b[c0 + col];
                ast_f(&a.zb[(size_t)(r0 + row) * LM + c0 + col], val);
                svt += val;
                sqt += val * val;
            }
            #pragma unroll
            for (int off = 1; off < 16; off <<= 1) {
                svt += __shfl_xor(svt, off, 16);
                sqt += __shfl_xor(sqt, off, 16);
            }
            if ((threadIdx.x & 15) == 0) {
                size_t base = (size_t)t * 2 * 64 * 64;
                ast_f(&a.part[base + (size_t)(r0 + row) * 64 + (bid & 63)], svt);
                ast_f(&a.part[base + 64 * 64 + (size_t)(r0 + row) * 64 + (bid & 63)], sqt);
            }
        }
        gridbar(a.flags, ++epoch, bid);
        // ====== Phase D: deterministic stats reduce + LN + GELU ============
        {
            int rowg = bid >> 2;                 // each block covers 1 row
            if (wave < 2) {
                size_t base = (size_t)t * 2 * 64 * 64 + (size_t)wave * 64 * 64;
                float v = ald_f(&a.part[base + (size_t)rowg * 64 + lane]);
                #pragma unroll
                for (int off = 32; off > 0; off >>= 1) v += __shfl_down(v, off, 64);
                if (lane == 0) redD[wave] = v;
            }
            __syncthreads();
            float mu = redD[0] * (1.f / LM);
            float var = redD[1] * (1.f / LM) - mu * mu;
            float inv = rsqrtf(var + 1e-5f);
            int e0 = (bid * 256 + threadIdx.x) * 2;      // B*LM = 131072
            float ge[2];
            #pragma unroll
            for (int j = 0; j < 2; j++) {
                int e = e0 + j;
                int cc = e & (LM - 1);
                float zn = (ald_f(&a.zb[e]) - mu) * inv * a.lng[cc] + a.lnb[cc];
                ge[j] = 0.5f * zn * (1.f + erff(zn * 0.70710678118654752f));
            }
            unsigned pk = (unsigned)f2bf(ge[0]) | ((unsigned)f2bf(ge[1]) << 16);
            ast_u((unsigned*)(a.zbb + e0), pk);
        }
        gridbar(a.flags, ++epoch, bid);
        // ============ Phase E: fc2 -> logits out[:, t, :] ==================
        if (bid < 128) {
            int c0 = (bid & 31) * 16;                    // XCD-aware
            int r0e = (bid >> 5) * 16;
            const int Kq = LM >> 2;                      // 512
            const short* ap = a.zbb + (size_t)(r0e + lrow) * LM + wave * Kq + ko8;
            const short* wpp = a.wfc2 + (size_t)(c0 + lrow) * LM + wave * Kq + ko8;
            floatx4 acc = {0.f, 0.f, 0.f, 0.f};
            #pragma unroll
            for (int half = 0; half < 2; ++half) {
                bf16x8 zreg[8];
                #pragma unroll
                for (int k = 0; k < 8; ++k)
                    zreg[k] = ald_b8(ap + half * 256 + k * 32);
                #pragma unroll
                for (int k = 0; k < 8; ++k)
                    acc = __builtin_amdgcn_mfma_f32_16x16x32_bf16(
                        zreg[k], *(const bf16x8*)(wpp + half * 256 + k * 32), acc, 0, 0, 0);
            }
            #pragma unroll
            for (int i = 0; i < 4; i++) lds[0][wave][lane][i] = acc[i];
            __syncthreads();
            int row = threadIdx.x >> 4, col = threadIdx.x & 15;
            int sl = (row >> 2) * 16 + col, rg = row & 3;
            float s = lds[0][0][sl][rg] + lds[0][1][sl][rg]
                    + lds[0][2][sl][rg] + lds[0][3][sl][rg];
            ast_f(&a.out[(size_t)(r0e + row) * ldl + (size_t)t * O_DIM + c0 + col],
                  s + a.fc2b[c0 + col]);
        }
        gridbar(a.flags, ++epoch, bid);
    }
}

// ===========================================================================
extern "C" void kernel_launch(void* const* d_in, const int* in_sizes, int n_in,
                              void* d_out, int out_size, void* d_ws, size_t ws_size,
                              hipStream_t stream) {
    const float* X        = (const float*)d_in[0];
    const float* Y0       = (const float*)d_in[1];
    const float* enc_Wih0 = (const float*)d_in[2];
    const float* enc_Whh0 = (const float*)d_in[3];
    const float* enc_bih0 = (const float*)d_in[4];
    const float* enc_bhh0 = (const float*)d_in[5];
    const float* enc_Wih1 = (const float*)d_in[6];
    const float* enc_Whh1 = (const float*)d_in[7];
    const float* enc_bih1 = (const float*)d_in[8];
    const float* enc_bhh1 = (const float*)d_in[9];
    const float* dec_Wih0 = (const float*)d_in[10];
    const float* dec_Whh0 = (const float*)d_in[11];
    const float* dec_bih0 = (const float*)d_in[12];
    const float* dec_bhh0 = (const float*)d_in[13];
    const float* dec_Wih1 = (const float*)d_in[14];
    const float* dec_Whh1 = (const float*)d_in[15];
    const float* dec_bih1 = (const float*)d_in[16];
    const float* dec_bhh1 = (const float*)d_in[17];
    const float* fc1_w    = (const float*)d_in[18];
    const float* fc1_b    = (const float*)d_in[19];
    const float* ln_g     = (const float*)d_in[20];
    const float* ln_b     = (const float*)d_in[21];
    const float* fc2_w    = (const float*)d_in[22];
    const float* fc2_b    = (const float*)d_in[23];
    float* out = (float*)d_out;

    // ---- workspace carve-up ----
    char* p = (char*)d_ws;
    auto carve = [&](size_t bytes) {
        void* r = p;
        p += (bytes + 255) & ~(size_t)255;
        return r;
    };
    short* Xt    = (short*)carve((size_t)TIN * B * N_IN * 2);
    short* seqA  = (short*)carve((size_t)TIN * B * M * 2);
    float* gi_ch = (float*)carve((size_t)CH * B * M3 * 4);
    short* we_ih0 = (short*)carve((size_t)M3 * N_IN * 2);
    short* we_hh0 = (short*)carve((size_t)M3 * M * 2);
    short* we_ih1 = (short*)carve((size_t)M3 * M * 2);
    short* we_hh1 = (short*)carve((size_t)M3 * M * 2);
    short* wd_ih0 = (short*)carve((size_t)M3 * O_DIM * 2);
    short* wd_hh0 = (short*)carve((size_t)M3 * M * 2);
    short* wd_ih1 = (short*)carve((size_t)M3 * M * 2);
    short* wd_hh1 = (short*)carve((size_t)M3 * M * 2);
    short* wfc1   = (short*)carve((size_t)LM * M * 2);
    short* wfc2   = (short*)carve((size_t)O_DIM * LM * 2);
    float* h0f = (float*)carve((size_t)B * M * 4);
    float* h1f = (float*)carve((size_t)B * M * 4);
    short* h0b = (short*)carve((size_t)2 * B * M * 2);   // ping-pong
    short* h1b = (short*)carve((size_t)2 * B * M * 2);
    short* yb  = (short*)carve((size_t)B * O_DIM * 2);
    float* zb  = (float*)carve((size_t)B * LM * 4);
    short* zbb = (short*)carve((size_t)B * LM * 2);
    float* part = (float*)carve((size_t)TDEC * 2 * 64 * 64 * 4);
    unsigned* eflags = (unsigned*)carve((size_t)NB * 32 * 4);  // padded flags
    unsigned* dflags = (unsigned*)carve((size_t)NB * 32 * 4);

    auto cast = [&](const float* src, short* dst, int n) {
        cast_bf<<<(n + 255) / 256, 256, 0, stream>>>(src, dst, n);
    };
    cast(enc_Wih0, we_ih0, M3 * N_IN);
    cast(enc_Whh0, we_hh0, M3 * M);
    cast(enc_Wih1, we_ih1, M3 * M);
    cast(enc_Whh1, we_hh1, M3 * M);
    cast(dec_Wih0, wd_ih0, M3 * O_DIM);
    cast(dec_Whh0, wd_hh0, M3 * M);
    cast(dec_Wih1, wd_ih1, M3 * M);
    cast(dec_Whh1, wd_hh1, M3 * M);
    cast(fc1_w, wfc1, LM * M);
    cast(fc2_w, wfc2, O_DIM * LM);
    cast(Y0, yb, B * O_DIM);
    transpose_X_bf<<<(TIN * B * N_IN) / 256, 256, 0, stream>>>(X, Xt);

    hipMemsetAsync(h0f, 0, (size_t)B * M * 4, stream);
    hipMemsetAsync(h1f, 0, (size_t)B * M * 4, stream);
    hipMemsetAsync(h0b, 0, (size_t)B * M * 2, stream);   // parity-0 buffer
    hipMemsetAsync(h1b, 0, (size_t)B * M * 2, stream);
    hipMemsetAsync(eflags, 0, (size_t)NB * 32 * 4, stream);
    hipMemsetAsync(dflags, 0, (size_t)NB * 32 * 4, stream);

    // -------------------- encoder (one mega-kernel) -----------------------
    EncArgs ea;
    ea.Xt = Xt; ea.seqA = seqA; ea.gi = gi_ch;
    ea.wih0 = we_ih0; ea.whh0 = we_hh0; ea.bih0 = enc_bih0; ea.bhh0 = enc_bhh0;
    ea.wih1 = we_ih1; ea.whh1 = we_hh1; ea.bih1 = enc_bih1; ea.bhh1 = enc_bhh1;
    ea.h0f = h0f; ea.h1f = h1f; ea.h0b = h0b; ea.h1b = h1b;
    ea.flags = eflags;
    enc_mega<<<dim3(NB), dim3(256), 0, stream>>>(ea);

    // -------------------- decoder (one mega-kernel) -----------------------
    DecArgs da;
    da.yb = yb;
    da.wih0 = wd_ih0; da.whh0 = wd_hh0; da.bih0 = dec_bih0; da.bhh0 = dec_bhh0;
    da.wih1 = wd_ih1; da.whh1 = wd_hh1; da.bih1 = dec_bih1; da.bhh1 = dec_bhh1;
    da.wfc1 = wfc1; da.fc1b = fc1_b;
    da.lng = ln_g; da.lnb = ln_b;
    da.wfc2 = wfc2; da.fc2b = fc2_b;
    da.h0f = h0f; da.h1f = h1f; da.h0b = h0b; da.h1b = h1b;
    da.zb = zb; da.zbb = zbb; da.part = part; da.out = out;
    da.flags = dflags;
    dec_mega<<<dim3(NB), dim3(256), 0, stream>>>(da);
}